// Round 14
// baseline (390.835 us; speedup 1.0000x reference)
//
#include <hip/hip_runtime.h>
#include <math.h>

typedef float  f32x4  __attribute__((ext_vector_type(4)));
typedef short  bf16x8 __attribute__((ext_vector_type(8)));
typedef unsigned short u16;
typedef unsigned int   u32;
typedef unsigned short u16x2 __attribute__((ext_vector_type(2)));
typedef unsigned short u16x4 __attribute__((ext_vector_type(4)));
typedef unsigned short u16x8 __attribute__((ext_vector_type(8)));

constexpr int Tn = 43, Hd = 1024, Nb = 512;

__device__ __forceinline__ u16 f2bf(float f) {
    u32 u = __float_as_uint(f);
    u32 r = u + 0x7FFFu + ((u >> 16) & 1u);
    return (u16)(r >> 16);
}
__device__ __forceinline__ float bf2f(u16 h) {
    return __uint_as_float(((u32)h) << 16);
}
__device__ __forceinline__ void cvt8(const float* f, u16x8* hi, u16x8* lo) {
    #pragma unroll
    for (int j = 0; j < 8; ++j) {
        u16 h = f2bf(f[j]);
        (*hi)[j] = h;
        (*lo)[j] = f2bf(f[j] - bf2f(h));
    }
}
__device__ __forceinline__ void cvt8h(const float* f, u16x8* hi) {
    #pragma unroll
    for (int j = 0; j < 8; ++j) (*hi)[j] = f2bf(f[j]);
}

// ---------------------------------------------------------------------------
// convT1: fp32 [K][N] -> bf16 HI plane only, transposed [N][K]
// ---------------------------------------------------------------------------
__device__ __forceinline__ void convT1_seg(const float* __restrict__ W,
                                           u16* __restrict__ Hi,
                                           int K, int N, int local, int t, char* lds)
{
    float (*tile)[33] = (float(*)[33])lds;
    const int tn = N >> 5;
    const int k0 = (local / tn) << 5, n0 = (local % tn) << 5;
    {
        int kk = t >> 3, nn = (t & 7) * 4;
        float4 v = *(const float4*)(W + (size_t)(k0 + kk) * N + n0 + nn);
        tile[kk][nn] = v.x; tile[kk][nn + 1] = v.y;
        tile[kk][nn + 2] = v.z; tile[kk][nn + 3] = v.w;
    }
    __syncthreads();
    {
        int nn = t >> 3, kk = (t & 7) * 4;
        u16x4 h;
        #pragma unroll
        for (int j = 0; j < 4; ++j) h[j] = f2bf(tile[kk + j][nn]);
        *(u16x4*)(Hi + (size_t)(n0 + nn) * K + k0 + kk) = h;
    }
}

// ---------------------------------------------------------------------------
// convN1: natural layout fp32 flat -> HI plane only (1024x512 per matrix)
// ---------------------------------------------------------------------------
__device__ __forceinline__ void convN1_seg(const float* __restrict__ src,
                                           u16* __restrict__ Hi, int local, int t)
{
    const size_t e = ((size_t)local * 256 + t) * 8;
    const float4* p = (const float4*)(src + e);
    float4 v0 = p[0], v1 = p[1];
    float f[8] = {v0.x, v0.y, v0.z, v0.w, v1.x, v1.y, v1.z, v1.w};
    u16x8 hv;
    cvt8h(f, &hv);
    *(u16x8*)(Hi + e) = hv;
}

// ---------------------------------------------------------------------------
// device GEMM: C = A@B^T.  A = hi(+lo) activation planes, B = HI weight plane.
// 2-term (1-term if A hi-only). 64x128 tile, BK=64, 4 waves, reg-staged.
// flags: 1=RELU 2=PLANES(hi+lo out) 4=SPLIT-K 8=A-hi-only 16=PLANES hi-only
// ---------------------------------------------------------------------------
__device__ __forceinline__ void gemm_dev(
    const u16* Ahi, const u16* Alo, int lda, size_t az,
    const u16* Bhi, int ldb, size_t bz,
    const float* bias, float* C, u16* CHi, u16* CLo, int ldc, int crz, int ccz,
    int M, int N, int K, int nz, int flags,
    float* Cp, size_t pstride, char* lds, int tid, int t0, int tstride)
{
    const bool RELU = flags & 1, PLANES = flags & 2, SPLIT = flags & 4;
    const bool A1 = flags & 8, PL1 = flags & 16;
    const int ncol = N >> 7;
    const int tpz = (M >> 6) * ncol;
    const int ntiles = nz * tpz;
    const int BOFF = A1 ? 8192 : 16384;      // B-plane base in LDS

    const int ra = tid >> 2, ga = tid & 3;
    const int rb = tid >> 1, gb = (tid & 1) << 1;
    const int wA  = ((ra >> 4) << 10) | (ga << 8) | ((((ra & 15) ^ (ga << 1)) & 15) << 4);
    const int wB0 = ((rb >> 4) << 10) | (gb << 8) | ((((rb & 15) ^ (gb << 1)) & 15) << 4);
    const int wB1 = ((rb >> 4) << 10) | ((gb + 1) << 8) | ((((rb & 15) ^ ((gb + 1) << 1)) & 15) << 4);
    const int wv = tid >> 6, lane = tid & 63;
    const int wr = wv >> 1, wc = wv & 1;
    const int l15 = lane & 15, l4 = lane >> 4;
    const int rsw = (l15 ^ (l4 << 1)) << 4;
    int fA[2], fB[4];
    #pragma unroll
    for (int m = 0; m < 2; ++m) fA[m] = (((wr << 1) + m) << 10) | (l4 << 8) | rsw;
    #pragma unroll
    for (int n = 0; n < 4; ++n) fB[n] = (((wc << 2) + n) << 10) | (l4 << 8) | rsw;

    for (int t = t0; t < ntiles; t += tstride) {
        const int z = t / tpz, r = t - z * tpz;
        const int tm = r / ncol;
        const int bm = tm << 6, bn = (r - tm * ncol) << 7;
        int kc = K, kb = 0;
        const u16 *ah = Ahi, *al = Alo, *bh = Bhi;
        if (SPLIT) { kc = K / nz; kb = z * kc; }
        else { ah += z * az; if (!A1) al += z * az; bh += z * bz; }

        const u16* pAh = ah + (size_t)(bm + ra) * lda + kb + ga * 8;
        const u16* pAl = A1 ? pAh : al + (size_t)(bm + ra) * lda + kb + ga * 8;
        const u16* pBh = bh + (size_t)(bn + rb) * ldb + kb + gb * 8;

        f32x4 acc[2][4] = {};

        uint4 sAh0 = *(const uint4*)pAh,        sAh1 = *(const uint4*)(pAh + 32);
        uint4 sAl0, sAl1;
        if (!A1) { sAl0 = *(const uint4*)pAl;   sAl1 = *(const uint4*)(pAl + 32); }
        uint4 sB00 = *(const uint4*)pBh,        sB01 = *(const uint4*)(pBh + 8);
        uint4 sB10 = *(const uint4*)(pBh + 32), sB11 = *(const uint4*)(pBh + 40);

        for (int k0 = 0; k0 < kc; k0 += 64) {
            __syncthreads();
            *(uint4*)(lds + wA)        = sAh0;
            *(uint4*)(lds + 4096 + wA) = sAh1;
            if (!A1) {
                *(uint4*)(lds + 8192 + wA)  = sAl0;
                *(uint4*)(lds + 12288 + wA) = sAl1;
            }
            *(uint4*)(lds + BOFF + wB0)        = sB00;
            *(uint4*)(lds + BOFF + wB1)        = sB01;
            *(uint4*)(lds + BOFF + 8192 + wB0) = sB10;
            *(uint4*)(lds + BOFF + 8192 + wB1) = sB11;
            __syncthreads();
            if (k0 + 64 < kc) {
                pAh += 64; pBh += 64;
                sAh0 = *(const uint4*)pAh;        sAh1 = *(const uint4*)(pAh + 32);
                if (!A1) {
                    pAl += 64;
                    sAl0 = *(const uint4*)pAl;    sAl1 = *(const uint4*)(pAl + 32);
                }
                sB00 = *(const uint4*)pBh;        sB01 = *(const uint4*)(pBh + 8);
                sB10 = *(const uint4*)(pBh + 32); sB11 = *(const uint4*)(pBh + 40);
            }
            #pragma unroll
            for (int h = 0; h < 2; ++h) {
                bf16x8 a8[2], c8[2], b8[4];
                #pragma unroll
                for (int m = 0; m < 2; ++m) {
                    a8[m] = *(const bf16x8*)(lds + (h << 12) + fA[m]);
                    if (!A1) c8[m] = *(const bf16x8*)(lds + 8192 + (h << 12) + fA[m]);
                }
                #pragma unroll
                for (int n = 0; n < 4; ++n)
                    b8[n] = *(const bf16x8*)(lds + BOFF + (h << 13) + fB[n]);
                #pragma unroll
                for (int m = 0; m < 2; ++m)
                    #pragma unroll
                    for (int n = 0; n < 4; ++n) {
                        acc[m][n] = __builtin_amdgcn_mfma_f32_16x16x32_bf16(a8[m], b8[n], acc[m][n], 0, 0, 0);
                        if (!A1)
                            acc[m][n] = __builtin_amdgcn_mfma_f32_16x16x32_bf16(c8[m], b8[n], acc[m][n], 0, 0, 0);
                    }
            }
        }

        #pragma unroll
        for (int n = 0; n < 4; ++n) {
            const int col = bn + (wc << 6) + n * 16 + l15;
            const float bv = (!SPLIT && bias) ? bias[col] : 0.f;
            const int colz = SPLIT ? col : col + z * ccz;
            #pragma unroll
            for (int m = 0; m < 2; ++m) {
                const int row0 = bm + (wr << 5) + m * 16 + l4 * 4;
                #pragma unroll
                for (int rg = 0; rg < 4; ++rg) {
                    const int row = row0 + rg;
                    float v = acc[m][n][rg];
                    if (SPLIT) {
                        Cp[z * pstride + (size_t)row * N + col] = v;
                    } else {
                        const int rowz = row + z * crz;
                        v += bv;
                        if (RELU) v = fmaxf(v, 0.f);
                        if (PL1) {
                            CHi[(size_t)rowz * ldc + colz] = f2bf(v);
                        } else if (PLANES) {
                            u16 hh = f2bf(v);
                            CHi[(size_t)rowz * ldc + colz] = hh;
                            CLo[(size_t)rowz * ldc + colz] = f2bf(v - bf2f(hh));
                        } else {
                            C[(size_t)rowz * ldc + colz] = v;
                        }
                    }
                }
            }
        }
    }
}

// ---------------------------------------------------------------------------
// gemm_G: G_h = Wk_h @ Wq_h^T from fp32 sources, convert-on-stage (reg path).
// ---------------------------------------------------------------------------
__device__ __forceinline__ void gemm_G(
    const float* k1w, const float* k2w, const float* q1w, const float* q2w,
    u16* GHi, char* lds, int tid, int t0, int tstride)
{
    const int ra = tid >> 2, ga = tid & 3;
    const int rb = tid >> 1, gb = (tid & 1) << 1;
    const int wA  = ((ra >> 4) << 10) | (ga << 8) | ((((ra & 15) ^ (ga << 1)) & 15) << 4);
    const int wB0 = ((rb >> 4) << 10) | (gb << 8) | ((((rb & 15) ^ (gb << 1)) & 15) << 4);
    const int wB1 = ((rb >> 4) << 10) | ((gb + 1) << 8) | ((((rb & 15) ^ ((gb + 1) << 1)) & 15) << 4);
    const int wv = tid >> 6, lane = tid & 63;
    const int wr = wv >> 1, wc = wv & 1;
    const int l15 = lane & 15, l4 = lane >> 4;
    const int rsw = (l15 ^ (l4 << 1)) << 4;
    int fA[2], fB[4];
    #pragma unroll
    for (int m = 0; m < 2; ++m) fA[m] = (((wr << 1) + m) << 10) | (l4 << 8) | rsw;
    #pragma unroll
    for (int n = 0; n < 4; ++n) fB[n] = (((wc << 2) + n) << 10) | (l4 << 8) | rsw;

    for (int t = t0; t < 256; t += tstride) {
        const int z = t >> 7, r = t & 127;
        const int bm = (r >> 3) << 6, bn = (r & 7) << 7;
        const float* pA = (z ? k2w : k1w) + (size_t)(bm + ra) * 512 + ga * 8;
        const float* pB = (z ? q2w : q1w) + (size_t)(bn + rb) * 512 + gb * 8;

        f32x4 acc[2][4] = {};
        float4 a0 = ((const float4*)pA)[0], a1 = ((const float4*)pA)[1];
        float4 b0 = ((const float4*)pB)[0], b1 = ((const float4*)pB)[1];
        float4 b2 = ((const float4*)pB)[2], b3 = ((const float4*)pB)[3];

        for (int k0 = 0; k0 < 512; k0 += 32) {
            u16x8 hi, lo;
            float fa[8] = {a0.x, a0.y, a0.z, a0.w, a1.x, a1.y, a1.z, a1.w};
            float fb[8] = {b0.x, b0.y, b0.z, b0.w, b1.x, b1.y, b1.z, b1.w};
            float fc[8] = {b2.x, b2.y, b2.z, b2.w, b3.x, b3.y, b3.z, b3.w};
            __syncthreads();
            cvt8(fa, &hi, &lo);
            *(u16x8*)(lds + wA) = hi;
            *(u16x8*)(lds + 4096 + wA) = lo;
            cvt8h(fb, &hi);
            *(u16x8*)(lds + 8192 + wB0) = hi;
            cvt8h(fc, &hi);
            *(u16x8*)(lds + 8192 + wB1) = hi;
            __syncthreads();
            if (k0 + 32 < 512) {
                pA += 32; pB += 32;
                a0 = ((const float4*)pA)[0]; a1 = ((const float4*)pA)[1];
                b0 = ((const float4*)pB)[0]; b1 = ((const float4*)pB)[1];
                b2 = ((const float4*)pB)[2]; b3 = ((const float4*)pB)[3];
            }
            bf16x8 a8[2], c8[2], b8[4];
            #pragma unroll
            for (int m = 0; m < 2; ++m) {
                a8[m] = *(const bf16x8*)(lds + fA[m]);
                c8[m] = *(const bf16x8*)(lds + 4096 + fA[m]);
            }
            #pragma unroll
            for (int n = 0; n < 4; ++n)
                b8[n] = *(const bf16x8*)(lds + 8192 + fB[n]);
            #pragma unroll
            for (int m = 0; m < 2; ++m)
                #pragma unroll
                for (int n = 0; n < 4; ++n) {
                    acc[m][n] = __builtin_amdgcn_mfma_f32_16x16x32_bf16(a8[m], b8[n], acc[m][n], 0, 0, 0);
                    acc[m][n] = __builtin_amdgcn_mfma_f32_16x16x32_bf16(c8[m], b8[n], acc[m][n], 0, 0, 0);
                }
        }

        #pragma unroll
        for (int n = 0; n < 4; ++n) {
            const int col = bn + (wc << 6) + n * 16 + l15;
            #pragma unroll
            for (int m = 0; m < 2; ++m) {
                const int row0 = bm + (wr << 5) + m * 16 + l4 * 4;
                #pragma unroll
                for (int rg = 0; rg < 4; ++rg) {
                    const int row = z * 1024 + row0 + rg;
                    GHi[(size_t)row * 1024 + col] = f2bf(acc[m][n][rg]);
                }
            }
        }
    }
}

// ===========================================================================
// shared arg block
// ===========================================================================
struct Args {
    const int* toks; const float* emb; const float* pos;
    const float *q1w, *q2w, *k1w, *k2w, *v1w, *v2w, *pw, *w1w, *w2w;
    const float *q1b, *q2b, *v1b, *v2b, *pb, *lg, *lb, *w1b, *w2b, *flw, *flb;
    u16 *GHi, *WpTHi, *W1THi, *W2THi, *WvNHi, *WvpHi;
    float *bU, *bvp;
    float* XclsF; u16 *XclsHi, *XclsLo;
    u16 *YHi, *YLo;
    float* U;
    float* Hb; u16 *HbHi, *HbLo;
    u16 *EHi, *ELo;
    float* Cp;
    int *cnt1, *cnt2;
    float* out;
};

// K1: G GEMM | cls embed | bU dots | convT1(pw) | convN1(v1,v2)  [2816 blocks]
__global__ __launch_bounds__(256, 4)
void k1_kernel(Args A)
{
    __shared__ alignas(16) char lds[16384];
    const int id = blockIdx.x, t = threadIdx.x;
    const size_t HO = (size_t)1024 * 512;
    if (id < 256) {
        gemm_G(A.k1w, A.k2w, A.q1w, A.q2w, A.GHi, lds, t, id, 256);
    } else if (id < 768) {                          // cls embed
        const int n = id - 256;
        const int tok = A.toks[n * Tn];
        float4 e = ((const float4*)(A.emb + (size_t)tok * Hd))[t];
        float4 p = ((const float4*)A.pos)[t];
        float f[4] = {e.x + p.x, e.y + p.y, e.z + p.z, e.w + p.w};
        ((float4*)(A.XclsF + (size_t)n * Hd))[t] = make_float4(f[0], f[1], f[2], f[3]);
        u16x4 hv, lv;
        #pragma unroll
        for (int j = 0; j < 4; ++j) {
            u16 h = f2bf(f[j]);
            hv[j] = h;
            lv[j] = f2bf(f[j] - bf2f(h));
        }
        *(u16x4*)(A.XclsHi + (size_t)n * Hd + t * 4) = hv;
        *(u16x4*)(A.XclsLo + (size_t)n * Hd + t * 4) = lv;
    } else if (id < 1280) {                         // bU = [Wk1@q1b | Wk2@q2b]
        const int b = id - 768;
        const int wave = t >> 6, lane = t & 63;
        const int jj = b * 4 + wave;
        const int head = jj >> 10, j = jj & 1023;
        const float* row = (head ? A.k2w : A.k1w) + (size_t)j * 512;
        const float* bqp = head ? A.q2b : A.q1b;
        float4 r0 = ((const float4*)row)[lane * 2];
        float4 r1 = ((const float4*)row)[lane * 2 + 1];
        float4 b0 = ((const float4*)bqp)[lane * 2];
        float4 b1 = ((const float4*)bqp)[lane * 2 + 1];
        float d = r0.x*b0.x + r0.y*b0.y + r0.z*b0.z + r0.w*b0.w
                + r1.x*b1.x + r1.y*b1.y + r1.z*b1.z + r1.w*b1.w;
        #pragma unroll
        for (int off = 32; off; off >>= 1) d += __shfl_xor(d, off);
        if (lane == 0) A.bU[jj] = d;
    } else if (id < 2304) {
        convT1_seg(A.pw, A.WpTHi, 1024, 1024, id - 1280, t, lds);
    } else if (id < 2560) {
        convN1_seg(A.v1w, A.WvNHi, id - 2304, t);
    } else {
        convN1_seg(A.v2w, A.WvNHi + HO, id - 2560, t);
    }
}

// K2: U GEMM | Wvp fold (1-term) | bvp | convT1(w1)              [4736 blocks]
__global__ __launch_bounds__(256, 4)
void k2_kernel(Args A)
{
    __shared__ alignas(16) char lds[32768];
    const int id = blockIdx.x, t = threadIdx.x;
    const size_t HO = (size_t)1024 * 512;
    if (id < 128)
        gemm_dev(A.XclsHi, A.XclsLo, 1024, 0, A.GHi, 1024, 0,
                 A.bU, A.U, nullptr, nullptr, 2048, 0, 0,
                 512, 2048, 1024, 1, 0, nullptr, 0, lds, t, id, 128);
    else if (id < 384)
        gemm_dev(A.WpTHi, nullptr, 1024, 512, A.WvNHi, 512, HO,
                 nullptr, nullptr, A.WvpHi, nullptr, 2048, 0, 1024,
                 1024, 1024, 512, 2, 8 | 16, nullptr, 0, lds, t, id - 128, 256);
    else if (id < 640) {
        const int wave = t >> 6, lane = t & 63;
        const int c = (id - 384) * 4 + wave;
        const int j0 = lane * 16;
        u16x8 h0 = *(const u16x8*)(A.WpTHi + (size_t)c * 1024 + j0);
        u16x8 h1 = *(const u16x8*)(A.WpTHi + (size_t)c * 1024 + j0 + 8);
        const float* bsrc = (j0 < 512) ? (A.v1b + j0) : (A.v2b + j0 - 512);
        float d = 0.f;
        #pragma unroll
        for (int j = 0; j < 8; ++j) d += bsrc[j] * bf2f(h0[j]);
        #pragma unroll
        for (int j = 0; j < 8; ++j) d += bsrc[8 + j] * bf2f(h1[j]);
        #pragma unroll
        for (int off = 32; off; off >>= 1) d += __shfl_xor(d, off);
        if (lane == 0) A.bvp[c] = d + A.pb[c];
    } else {
        convT1_seg(A.w1w, A.W1THi, 1024, 4096, id - 640, t, lds);
    }
}

// K3: single-pass attention, x cached in LDS as bf16             [512 blocks]
__global__ __launch_bounds__(512, 1)
void k3_kernel(Args A)
{
    __shared__ float us[2048];
    __shared__ float ps[128];
    __shared__ u16 xc[Tn * 1024];
    const int n = blockIdx.x, tid = threadIdx.x;
    ((float4*)us)[tid] = ((const float4*)(A.U + (size_t)n * 2048))[tid];
    __syncthreads();

    const int wave = tid >> 6, lane = tid & 63;
    const int* tk = A.toks + n * Tn;
    for (int s = wave; s < Tn; s += 8) {
        const int tok = tk[s];
        const float4* er = (const float4*)(A.emb + (size_t)tok * Hd);
        const float4* pr = (const float4*)(A.pos + (size_t)s * Hd);
        float d1 = 0.f, d2 = 0.f;
        #pragma unroll
        for (int i = 0; i < 4; ++i) {
            const int c = i * 64 + lane;
            float4 e = er[c], p = pr[c];
            float x0 = e.x + p.x, x1 = e.y + p.y, x2 = e.z + p.z, x3 = e.w + p.w;
            u16x4 xv;
            xv[0] = f2bf(x0); xv[1] = f2bf(x1); xv[2] = f2bf(x2); xv[3] = f2bf(x3);
            *(u16x4*)(xc + s * 1024 + c * 4) = xv;
            const float* u1 = us + c * 4;
            const float* u2 = us + 1024 + c * 4;
            d1 += x0 * u1[0] + x1 * u1[1] + x2 * u1[2] + x3 * u1[3];
            d2 += x0 * u2[0] + x1 * u2[1] + x2 * u2[2] + x3 * u2[3];
        }
        #pragma unroll
        for (int off = 32; off; off >>= 1) {
            d1 += __shfl_xor(d1, off);
            d2 += __shfl_xor(d2, off);
        }
        if (lane == 0) {
            ps[s]      = d1 * 0.044194173824159216f;   // 1/sqrt(512)
            ps[64 + s] = d2 * 0.044194173824159216f;
        }
    }
    __syncthreads();
    if (wave < 2) {
        float v = (lane < Tn) ? ps[wave * 64 + lane] : -INFINITY;
        float mx = v;
        #pragma unroll
        for (int off = 32; off; off >>= 1) mx = fmaxf(mx, __shfl_xor(mx, off));
        float e = (lane < Tn) ? __expf(v - mx) : 0.f;
        float sum = e;
        #pragma unroll
        for (int off = 32; off; off >>= 1) sum += __shfl_xor(sum, off);
        if (lane < Tn) ps[wave * 64 + lane] = e / sum;
    }
    __syncthreads();

    float a1x = 0.f, a1y = 0.f, a2x = 0.f, a2y = 0.f;
    for (int s = 0; s < Tn; ++s) {
        const float p1 = ps[s], p2 = ps[64 + s];
        u16x2 xv = *(const u16x2*)(xc + s * 1024 + tid * 2);
        const float x0 = bf2f(xv[0]), x1 = bf2f(xv[1]);
        a1x = fmaf(p1, x0, a1x); a1y = fmaf(p1, x1, a1y);
        a2x = fmaf(p2, x0, a2x); a2y = fmaf(p2, x1, a2y);
    }
    u16x2 h1, l1, h2, l2;
    u16 h;
    h = f2bf(a1x); h1[0] = h; l1[0] = f2bf(a1x - bf2f(h));
    h = f2bf(a1y); h1[1] = h; l1[1] = f2bf(a1y - bf2f(h));
    h = f2bf(a2x); h2[0] = h; l2[0] = f2bf(a2x - bf2f(h));
    h = f2bf(a2y); h2[1] = h; l2[1] = f2bf(a2y - bf2f(h));
    const size_t o = (size_t)n * 2048 + tid * 2;
    *(u16x2*)(A.YHi + o) = h1;          *(u16x2*)(A.YLo + o) = l1;
    *(u16x2*)(A.YHi + o + 1024) = h2;   *(u16x2*)(A.YLo + o + 1024) = l2;
}

// K4: Hb partials (split-K=8) + fused last-block reduce+LN | convT1(w2)
//     [4608 blocks: 512 GEMM tiles + 4096 conv]
__global__ __launch_bounds__(256, 4)
void k4_kernel(Args A)
{
    __shared__ alignas(16) char lds[32768];
    const int id = blockIdx.x, t = threadIdx.x;
    const size_t P = (size_t)Nb * Hd;
    if (id < 512) {
        gemm_dev(A.YHi, A.YLo, 2048, 0, A.WvpHi, 2048, 0,
                 nullptr, nullptr, nullptr, nullptr, 0, 0, 0,
                 512, 1024, 2048, 8, 4, A.Cp, P, lds, t, id, 512);
        // semaphore: 64 contributors per m-tile (8 z x 8 n)
        const int tm = (id & 63) >> 3;
        __threadfence();
        int* flag = (int*)lds;
        if (t == 0) *flag = atomicAdd(A.cnt1 + tm, 1);
        __syncthreads();
        if (*flag == 63) {
            __threadfence();
            float* shr = (float*)(lds + 64);
            const int lane = t & 63, w = t >> 6;
            for (int row = tm * 64; row < tm * 64 + 64; ++row) {
                const size_t base = (size_t)row * Hd;
                float4 v = ((const float4*)A.bvp)[t];
                float4 xcv = ((const float4*)(A.XclsF + base))[t];
                v.x += xcv.x; v.y += xcv.y; v.z += xcv.z; v.w += xcv.w;
                #pragma unroll
                for (int z = 0; z < 8; ++z) {
                    float4 c = ((const float4*)(A.Cp + z * P + base))[t];
                    v.x += c.x; v.y += c.y; v.z += c.z; v.w += c.w;
                }
                float s = v.x + v.y + v.z + v.w;
                float q = v.x*v.x + v.y*v.y + v.z*v.z + v.w*v.w;
                #pragma unroll
                for (int off = 32; off; off >>= 1) {
                    s += __shfl_xor(s, off);
                    q += __shfl_xor(q, off);
                }
                if (lane == 0) { shr[w] = s; shr[4 + w] = q; }
                __syncthreads();
                s = shr[0] + shr[1] + shr[2] + shr[3];
                q = shr[4] + shr[5] + shr[6] + shr[7];
                __syncthreads();
                const float mean = s * (1.f / Hd);
                const float var = q * (1.f / Hd) - mean * mean;
                const float rstd = rsqrtf(var + 1e-5f);
                float4 gv = ((const float4*)A.lg)[t];
                float4 bv = ((const float4*)A.lb)[t];
                float f[4];
                f[0] = (v.x - mean) * rstd * gv.x + bv.x;
                f[1] = (v.y - mean) * rstd * gv.y + bv.y;
                f[2] = (v.z - mean) * rstd * gv.z + bv.z;
                f[3] = (v.w - mean) * rstd * gv.w + bv.w;
                ((float4*)(A.Hb + base))[t] = make_float4(f[0], f[1], f[2], f[3]);
                u16x4 hv, lv;
                #pragma unroll
                for (int j = 0; j < 4; ++j) {
                    u16 hh = f2bf(f[j]);
                    hv[j] = hh;
                    lv[j] = f2bf(f[j] - bf2f(hh));
                }
                *(u16x4*)(A.HbHi + base + t * 4) = hv;
                *(u16x4*)(A.HbLo + base + t * 4) = lv;
            }
        }
    } else {
        convT1_seg(A.w2w, A.W2THi, 4096, 1024, id - 512, t, lds);
    }
}

// K6: E = relu(Hb @ W1 + w1b) -> hi/lo planes                    [256 blocks]
__global__ __launch_bounds__(256, 4)
void k6_kernel(Args A)
{
    __shared__ alignas(16) char lds[32768];
    gemm_dev(A.HbHi, A.HbLo, 1024, 0, A.W1THi, 1024, 0,
             A.w1b, nullptr, A.EHi, A.ELo, 4096, 0, 0,
             512, 4096, 1024, 1, 3, nullptr, 0, lds, threadIdx.x, blockIdx.x, 256);
}

// K7: w2 partials (split-K=4) + fused last-block reduce+LN+sigmoid [256 blocks]
__global__ __launch_bounds__(256, 4)
void k7_kernel(Args A)
{
    __shared__ alignas(16) char lds[32768];
    const int id = blockIdx.x, t = threadIdx.x;
    const size_t P = (size_t)Nb * Hd;
    gemm_dev(A.EHi, A.ELo, 4096, 0, A.W2THi, 4096, 0,
             nullptr, nullptr, nullptr, nullptr, 0, 0, 0,
             512, 1024, 4096, 4, 4, A.Cp, P, lds, t, id, 256);
    // semaphore: 32 contributors per m-tile (4 z x 8 n)
    const int tm = (id & 63) >> 3;
    __threadfence();
    int* flag = (int*)lds;
    if (t == 0) *flag = atomicAdd(A.cnt2 + tm, 1);
    __syncthreads();
    if (*flag == 31) {
        __threadfence();
        float* shr = (float*)(lds + 64);
        const int lane = t & 63, w = t >> 6;
        for (int row = tm * 64; row < tm * 64 + 64; ++row) {
            const size_t base = (size_t)row * Hd;
            float4 v = ((const float4*)A.w2b)[t];
            float4 hh4 = ((const float4*)(A.Hb + base))[t];
            v.x += hh4.x; v.y += hh4.y; v.z += hh4.z; v.w += hh4.w;
            #pragma unroll
            for (int z = 0; z < 4; ++z) {
                float4 c = ((const float4*)(A.Cp + z * P + base))[t];
                v.x += c.x; v.y += c.y; v.z += c.z; v.w += c.w;
            }
            float s = v.x + v.y + v.z + v.w;
            float q = v.x*v.x + v.y*v.y + v.z*v.z + v.w*v.w;
            #pragma unroll
            for (int off = 32; off; off >>= 1) {
                s += __shfl_xor(s, off);
                q += __shfl_xor(q, off);
            }
            if (lane == 0) { shr[w] = s; shr[4 + w] = q; }
            __syncthreads();
            s = shr[0] + shr[1] + shr[2] + shr[3];
            q = shr[4] + shr[5] + shr[6] + shr[7];
            __syncthreads();
            const float mean = s * (1.f / Hd);
            const float var = q * (1.f / Hd) - mean * mean;
            const float rstd = rsqrtf(var + 1e-5f);
            float4 gv = ((const float4*)A.lg)[t];
            float4 bv = ((const float4*)A.lb)[t];
            float4 wv = ((const float4*)A.flw)[t];
            float d = ((v.x - mean) * rstd * gv.x + bv.x) * wv.x
                    + ((v.y - mean) * rstd * gv.y + bv.y) * wv.y
                    + ((v.z - mean) * rstd * gv.z + bv.z) * wv.z
                    + ((v.w - mean) * rstd * gv.w + bv.w) * wv.w;
            #pragma unroll
            for (int off = 32; off; off >>= 1) d += __shfl_xor(d, off);
            if (lane == 0) shr[8 + w] = d;
            __syncthreads();
            if (t == 0) {
                float z2 = shr[8] + shr[9] + shr[10] + shr[11] + A.flb[0];
                A.out[row] = 1.f / (1.f + expf(-z2));
            }
            __syncthreads();
        }
    }
}

// ===========================================================================
// host
// ===========================================================================
extern "C" void kernel_launch(void* const* d_in, const int* in_sizes, int n_in,
                              void* d_out, int out_size, void* d_ws, size_t ws_size,
                              hipStream_t stream)
{
    Args A;
    A.toks = (const int*)d_in[0];
    A.emb  = (const float*)d_in[1];
    A.pos  = (const float*)d_in[2];
    A.q1w = (const float*)d_in[3];  A.q1b = (const float*)d_in[4];
    A.k1w = (const float*)d_in[5];
    A.v1w = (const float*)d_in[7];  A.v1b = (const float*)d_in[8];
    A.q2w = (const float*)d_in[9];  A.q2b = (const float*)d_in[10];
    A.k2w = (const float*)d_in[11];
    A.v2w = (const float*)d_in[13]; A.v2b = (const float*)d_in[14];
    A.pw  = (const float*)d_in[15]; A.pb  = (const float*)d_in[16];
    A.lg  = (const float*)d_in[17]; A.lb  = (const float*)d_in[18];
    A.w1w = (const float*)d_in[19]; A.w1b = (const float*)d_in[20];
    A.w2w = (const float*)d_in[21]; A.w2b = (const float*)d_in[22];
    A.flw = (const float*)d_in[23]; A.flb = (const float*)d_in[24];
    A.out = (float*)d_out;
    char* wsb = (char*)d_ws;

    size_t off = 0;
    auto alloc = [&](size_t bytes) { size_t o = off; off = (off + bytes + 255) & ~(size_t)255; return o; };

    A.GHi   = (u16*)(wsb + alloc(2048 * 1024 * 2));
    A.WpTHi = (u16*)(wsb + alloc(1024 * 1024 * 2));
    A.W1THi = (u16*)(wsb + alloc(4096 * 1024 * 2));
    A.W2THi = (u16*)(wsb + alloc(1024 * 4096 * 2));
    A.WvNHi = (u16*)(wsb + alloc(2 * 1024 * 512 * 2));
    A.WvpHi = (u16*)(wsb + alloc(1024 * 2048 * 2));
    A.bU    = (float*)(wsb + alloc(2048 * 4));
    A.bvp   = (float*)(wsb + alloc(1024 * 4));
    A.XclsF = (float*)(wsb + alloc((size_t)Nb * Hd * 4));
    A.XclsHi= (u16*)(wsb + alloc((size_t)Nb * Hd * 2));
    A.XclsLo= (u16*)(wsb + alloc((size_t)Nb * Hd * 2));
    A.U     = (float*)(wsb + alloc((size_t)Nb * 2048 * 4));
    A.YHi   = (u16*)(wsb + alloc((size_t)Nb * 2048 * 2));
    A.YLo   = (u16*)(wsb + alloc((size_t)Nb * 2048 * 2));
    A.Hb    = (float*)(wsb + alloc((size_t)Nb * Hd * 4));
    A.HbHi  = (u16*)(wsb + alloc((size_t)Nb * Hd * 2));
    A.HbLo  = (u16*)(wsb + alloc((size_t)Nb * Hd * 2));
    A.EHi   = (u16*)(wsb + alloc((size_t)Nb * 4096 * 2));
    A.ELo   = (u16*)(wsb + alloc((size_t)Nb * 4096 * 2));
    A.Cp    = (float*)(wsb + alloc((size_t)8 * Nb * Hd * 4));
    A.cnt1  = (int*)(wsb + alloc(64 * 4));
    A.cnt2  = (int*)(wsb + alloc(64 * 4));

    hipMemsetAsync(A.cnt1, 0, 128 * 4, stream);   // cnt1+cnt2 contiguous

    k1_kernel<<<2816, 256, 0, stream>>>(A);
    k2_kernel<<<4736, 256, 0, stream>>>(A);
    k3_kernel<<<512,  512, 0, stream>>>(A);
    k4_kernel<<<4608, 256, 0, stream>>>(A);
    k6_kernel<<<256,  256, 0, stream>>>(A);
    k7_kernel<<<256,  256, 0, stream>>>(A);
}

// Round 15
// 114.128 us; speedup vs baseline: 3.4245x; 3.4245x over previous
//
#include <hip/hip_runtime.h>
#include <math.h>

typedef float  f32x4  __attribute__((ext_vector_type(4)));
typedef short  bf16x8 __attribute__((ext_vector_type(8)));
typedef unsigned short u16;
typedef unsigned int   u32;
typedef unsigned short u16x2 __attribute__((ext_vector_type(2)));
typedef unsigned short u16x4 __attribute__((ext_vector_type(4)));
typedef unsigned short u16x8 __attribute__((ext_vector_type(8)));

constexpr int Tn = 43, Hd = 1024, Nb = 512;

__device__ __forceinline__ u16 f2bf(float f) {
    u32 u = __float_as_uint(f);
    u32 r = u + 0x7FFFu + ((u >> 16) & 1u);
    return (u16)(r >> 16);
}
__device__ __forceinline__ float bf2f(u16 h) {
    return __uint_as_float(((u32)h) << 16);
}
__device__ __forceinline__ void cvt8(const float* f, u16x8* hi, u16x8* lo) {
    #pragma unroll
    for (int j = 0; j < 8; ++j) {
        u16 h = f2bf(f[j]);
        (*hi)[j] = h;
        (*lo)[j] = f2bf(f[j] - bf2f(h));
    }
}
__device__ __forceinline__ void cvt8h(const float* f, u16x8* hi) {
    #pragma unroll
    for (int j = 0; j < 8; ++j) (*hi)[j] = f2bf(f[j]);
}

// ---------------------------------------------------------------------------
// convT1: fp32 [K][N] -> bf16 HI plane only, transposed [N][K]
// ---------------------------------------------------------------------------
__device__ __forceinline__ void convT1_seg(const float* __restrict__ W,
                                           u16* __restrict__ Hi,
                                           int K, int N, int local, int t, char* lds)
{
    float (*tile)[33] = (float(*)[33])lds;
    const int tn = N >> 5;
    const int k0 = (local / tn) << 5, n0 = (local % tn) << 5;
    {
        int kk = t >> 3, nn = (t & 7) * 4;
        float4 v = *(const float4*)(W + (size_t)(k0 + kk) * N + n0 + nn);
        tile[kk][nn] = v.x; tile[kk][nn + 1] = v.y;
        tile[kk][nn + 2] = v.z; tile[kk][nn + 3] = v.w;
    }
    __syncthreads();
    {
        int nn = t >> 3, kk = (t & 7) * 4;
        u16x4 h;
        #pragma unroll
        for (int j = 0; j < 4; ++j) h[j] = f2bf(tile[kk + j][nn]);
        *(u16x4*)(Hi + (size_t)(n0 + nn) * K + k0 + kk) = h;
    }
}

// ---------------------------------------------------------------------------
// convN1: natural layout fp32 flat -> HI plane only (1024x512 per matrix)
// ---------------------------------------------------------------------------
__device__ __forceinline__ void convN1_seg(const float* __restrict__ src,
                                           u16* __restrict__ Hi, int local, int t)
{
    const size_t e = ((size_t)local * 256 + t) * 8;
    const float4* p = (const float4*)(src + e);
    float4 v0 = p[0], v1 = p[1];
    float f[8] = {v0.x, v0.y, v0.z, v0.w, v1.x, v1.y, v1.z, v1.w};
    u16x8 hv;
    cvt8h(f, &hv);
    *(u16x8*)(Hi + e) = hv;
}

// ---------------------------------------------------------------------------
// device GEMM: C = A@B^T.  A = hi(+lo) activation planes, B = HI weight plane.
// 2-term (1-term if A hi-only). 64x128 tile, BK=64 (two 32-k halves, halved
// barrier count), 4 waves, reg-staged loads (full K-step flight time).
// LDS (2-term): Ahi[0,8K) Alo[8K,16K) B[16K,32K); A1: Ahi[0,8K) B[8K,24K).
// flags: 1=RELU 2=PLANES(hi+lo out) 4=SPLIT-K 8=A-hi-only 16=PLANES hi-only
// ---------------------------------------------------------------------------
__device__ __forceinline__ void gemm_dev(
    const u16* Ahi, const u16* Alo, int lda, size_t az,
    const u16* Bhi, int ldb, size_t bz,
    const float* bias, float* C, u16* CHi, u16* CLo, int ldc, int crz, int ccz,
    int M, int N, int K, int nz, int flags,
    float* Cp, size_t pstride, char* lds, int tid, int t0, int tstride)
{
    const bool RELU = flags & 1, PLANES = flags & 2, SPLIT = flags & 4;
    const bool A1 = flags & 8, PL1 = flags & 16;
    const int ncol = N >> 7;
    const int tpz = (M >> 6) * ncol;
    const int ntiles = nz * tpz;
    const int BOFF = A1 ? 8192 : 16384;      // B-plane base in LDS

    const int ra = tid >> 2, ga = tid & 3;
    const int rb = tid >> 1, gb = (tid & 1) << 1;
    const int wA  = ((ra >> 4) << 10) | (ga << 8) | ((((ra & 15) ^ (ga << 1)) & 15) << 4);
    const int wB0 = ((rb >> 4) << 10) | (gb << 8) | ((((rb & 15) ^ (gb << 1)) & 15) << 4);
    const int wB1 = ((rb >> 4) << 10) | ((gb + 1) << 8) | ((((rb & 15) ^ ((gb + 1) << 1)) & 15) << 4);
    const int wv = tid >> 6, lane = tid & 63;
    const int wr = wv >> 1, wc = wv & 1;
    const int l15 = lane & 15, l4 = lane >> 4;
    const int rsw = (l15 ^ (l4 << 1)) << 4;
    int fA[2], fB[4];
    #pragma unroll
    for (int m = 0; m < 2; ++m) fA[m] = (((wr << 1) + m) << 10) | (l4 << 8) | rsw;
    #pragma unroll
    for (int n = 0; n < 4; ++n) fB[n] = (((wc << 2) + n) << 10) | (l4 << 8) | rsw;

    for (int t = t0; t < ntiles; t += tstride) {
        const int z = t / tpz, r = t - z * tpz;
        const int tm = r / ncol;
        const int bm = tm << 6, bn = (r - tm * ncol) << 7;
        int kc = K, kb = 0;
        const u16 *ah = Ahi, *al = Alo, *bh = Bhi;
        if (SPLIT) { kc = K / nz; kb = z * kc; }
        else { ah += z * az; if (!A1) al += z * az; bh += z * bz; }

        const u16* pAh = ah + (size_t)(bm + ra) * lda + kb + ga * 8;
        const u16* pAl = A1 ? pAh : al + (size_t)(bm + ra) * lda + kb + ga * 8;
        const u16* pBh = bh + (size_t)(bn + rb) * ldb + kb + gb * 8;

        f32x4 acc[2][4] = {};

        // prologue: load k-step 0 (two 32-k halves) into registers
        uint4 sAh0 = *(const uint4*)pAh,        sAh1 = *(const uint4*)(pAh + 32);
        uint4 sAl0, sAl1;
        if (!A1) { sAl0 = *(const uint4*)pAl;   sAl1 = *(const uint4*)(pAl + 32); }
        uint4 sB00 = *(const uint4*)pBh,        sB01 = *(const uint4*)(pBh + 8);
        uint4 sB10 = *(const uint4*)(pBh + 32), sB11 = *(const uint4*)(pBh + 40);

        for (int k0 = 0; k0 < kc; k0 += 64) {
            __syncthreads();
            *(uint4*)(lds + wA)        = sAh0;
            *(uint4*)(lds + 4096 + wA) = sAh1;
            if (!A1) {
                *(uint4*)(lds + 8192 + wA)  = sAl0;
                *(uint4*)(lds + 12288 + wA) = sAl1;
            }
            *(uint4*)(lds + BOFF + wB0)        = sB00;
            *(uint4*)(lds + BOFF + wB1)        = sB01;
            *(uint4*)(lds + BOFF + 8192 + wB0) = sB10;
            *(uint4*)(lds + BOFF + 8192 + wB1) = sB11;
            __syncthreads();
            if (k0 + 64 < kc) {
                pAh += 64; pBh += 64;
                sAh0 = *(const uint4*)pAh;        sAh1 = *(const uint4*)(pAh + 32);
                if (!A1) {
                    pAl += 64;
                    sAl0 = *(const uint4*)pAl;    sAl1 = *(const uint4*)(pAl + 32);
                }
                sB00 = *(const uint4*)pBh;        sB01 = *(const uint4*)(pBh + 8);
                sB10 = *(const uint4*)(pBh + 32); sB11 = *(const uint4*)(pBh + 40);
            }
            #pragma unroll
            for (int h = 0; h < 2; ++h) {
                bf16x8 a8[2], c8[2], b8[4];
                #pragma unroll
                for (int m = 0; m < 2; ++m) {
                    a8[m] = *(const bf16x8*)(lds + (h << 12) + fA[m]);
                    if (!A1) c8[m] = *(const bf16x8*)(lds + 8192 + (h << 12) + fA[m]);
                }
                #pragma unroll
                for (int n = 0; n < 4; ++n)
                    b8[n] = *(const bf16x8*)(lds + BOFF + (h << 13) + fB[n]);
                #pragma unroll
                for (int m = 0; m < 2; ++m)
                    #pragma unroll
                    for (int n = 0; n < 4; ++n) {
                        acc[m][n] = __builtin_amdgcn_mfma_f32_16x16x32_bf16(a8[m], b8[n], acc[m][n], 0, 0, 0);
                        if (!A1)
                            acc[m][n] = __builtin_amdgcn_mfma_f32_16x16x32_bf16(c8[m], b8[n], acc[m][n], 0, 0, 0);
                    }
            }
        }

        #pragma unroll
        for (int n = 0; n < 4; ++n) {
            const int col = bn + (wc << 6) + n * 16 + l15;
            const float bv = (!SPLIT && bias) ? bias[col] : 0.f;
            const int colz = SPLIT ? col : col + z * ccz;
            #pragma unroll
            for (int m = 0; m < 2; ++m) {
                const int row0 = bm + (wr << 5) + m * 16 + l4 * 4;
                #pragma unroll
                for (int rg = 0; rg < 4; ++rg) {
                    const int row = row0 + rg;
                    float v = acc[m][n][rg];
                    if (SPLIT) {
                        Cp[z * pstride + (size_t)row * N + col] = v;
                    } else {
                        const int rowz = row + z * crz;
                        v += bv;
                        if (RELU) v = fmaxf(v, 0.f);
                        if (PL1) {
                            CHi[(size_t)rowz * ldc + colz] = f2bf(v);
                        } else if (PLANES) {
                            u16 hh = f2bf(v);
                            CHi[(size_t)rowz * ldc + colz] = hh;
                            CLo[(size_t)rowz * ldc + colz] = f2bf(v - bf2f(hh));
                        } else {
                            C[(size_t)rowz * ldc + colz] = v;
                        }
                    }
                }
            }
        }
    }
}

// ---------------------------------------------------------------------------
// gemm_G: G_h = Wk_h @ Wq_h^T from fp32 sources, convert-on-stage (reg path).
// A = Wk hi+lo, B = Wq hi only -> 2-term. Output G HI plane only. (BK=32)
// ---------------------------------------------------------------------------
__device__ __forceinline__ void gemm_G(
    const float* k1w, const float* k2w, const float* q1w, const float* q2w,
    u16* GHi, char* lds, int tid, int t0, int tstride)
{
    const int ra = tid >> 2, ga = tid & 3;
    const int rb = tid >> 1, gb = (tid & 1) << 1;
    const int wA  = ((ra >> 4) << 10) | (ga << 8) | ((((ra & 15) ^ (ga << 1)) & 15) << 4);
    const int wB0 = ((rb >> 4) << 10) | (gb << 8) | ((((rb & 15) ^ (gb << 1)) & 15) << 4);
    const int wB1 = ((rb >> 4) << 10) | ((gb + 1) << 8) | ((((rb & 15) ^ ((gb + 1) << 1)) & 15) << 4);
    const int wv = tid >> 6, lane = tid & 63;
    const int wr = wv >> 1, wc = wv & 1;
    const int l15 = lane & 15, l4 = lane >> 4;
    const int rsw = (l15 ^ (l4 << 1)) << 4;
    int fA[2], fB[4];
    #pragma unroll
    for (int m = 0; m < 2; ++m) fA[m] = (((wr << 1) + m) << 10) | (l4 << 8) | rsw;
    #pragma unroll
    for (int n = 0; n < 4; ++n) fB[n] = (((wc << 2) + n) << 10) | (l4 << 8) | rsw;

    for (int t = t0; t < 256; t += tstride) {
        const int z = t >> 7, r = t & 127;
        const int bm = (r >> 3) << 6, bn = (r & 7) << 7;
        const float* pA = (z ? k2w : k1w) + (size_t)(bm + ra) * 512 + ga * 8;
        const float* pB = (z ? q2w : q1w) + (size_t)(bn + rb) * 512 + gb * 8;

        f32x4 acc[2][4] = {};
        float4 a0 = ((const float4*)pA)[0], a1 = ((const float4*)pA)[1];
        float4 b0 = ((const float4*)pB)[0], b1 = ((const float4*)pB)[1];
        float4 b2 = ((const float4*)pB)[2], b3 = ((const float4*)pB)[3];

        for (int k0 = 0; k0 < 512; k0 += 32) {
            u16x8 hi, lo;
            float fa[8] = {a0.x, a0.y, a0.z, a0.w, a1.x, a1.y, a1.z, a1.w};
            float fb[8] = {b0.x, b0.y, b0.z, b0.w, b1.x, b1.y, b1.z, b1.w};
            float fc[8] = {b2.x, b2.y, b2.z, b2.w, b3.x, b3.y, b3.z, b3.w};
            __syncthreads();
            cvt8(fa, &hi, &lo);
            *(u16x8*)(lds + wA) = hi;
            *(u16x8*)(lds + 4096 + wA) = lo;
            cvt8h(fb, &hi);
            *(u16x8*)(lds + 8192 + wB0) = hi;
            cvt8h(fc, &hi);
            *(u16x8*)(lds + 8192 + wB1) = hi;
            __syncthreads();
            if (k0 + 32 < 512) {
                pA += 32; pB += 32;
                a0 = ((const float4*)pA)[0]; a1 = ((const float4*)pA)[1];
                b0 = ((const float4*)pB)[0]; b1 = ((const float4*)pB)[1];
                b2 = ((const float4*)pB)[2]; b3 = ((const float4*)pB)[3];
            }
            bf16x8 a8[2], c8[2], b8[4];
            #pragma unroll
            for (int m = 0; m < 2; ++m) {
                a8[m] = *(const bf16x8*)(lds + fA[m]);
                c8[m] = *(const bf16x8*)(lds + 4096 + fA[m]);
            }
            #pragma unroll
            for (int n = 0; n < 4; ++n)
                b8[n] = *(const bf16x8*)(lds + 8192 + fB[n]);
            #pragma unroll
            for (int m = 0; m < 2; ++m)
                #pragma unroll
                for (int n = 0; n < 4; ++n) {
                    acc[m][n] = __builtin_amdgcn_mfma_f32_16x16x32_bf16(a8[m], b8[n], acc[m][n], 0, 0, 0);
                    acc[m][n] = __builtin_amdgcn_mfma_f32_16x16x32_bf16(c8[m], b8[n], acc[m][n], 0, 0, 0);
                }
        }

        #pragma unroll
        for (int n = 0; n < 4; ++n) {
            const int col = bn + (wc << 6) + n * 16 + l15;
            #pragma unroll
            for (int m = 0; m < 2; ++m) {
                const int row0 = bm + (wr << 5) + m * 16 + l4 * 4;
                #pragma unroll
                for (int rg = 0; rg < 4; ++rg) {
                    const int row = z * 1024 + row0 + rg;
                    GHi[(size_t)row * 1024 + col] = f2bf(acc[m][n][rg]);
                }
            }
        }
    }
}

// ===========================================================================
// shared arg block
// ===========================================================================
struct Args {
    const int* toks; const float* emb; const float* pos;
    const float *q1w, *q2w, *k1w, *k2w, *v1w, *v2w, *pw, *w1w, *w2w;
    const float *q1b, *q2b, *v1b, *v2b, *pb, *lg, *lb, *w1b, *w2b, *flw, *flb;
    u16 *GHi, *WpTHi, *W1THi, *W2THi, *WvNHi, *WvpHi;
    float *bU, *bvp;
    float* XclsF; u16 *XclsHi, *XclsLo;
    float* U; u16 *YHi, *YLo;
    float* Hb; u16 *HbHi, *HbLo;
    u16 *EHi, *ELo;
    float* Cp;
    float* out;
};

// K1: G GEMM | cls embed | bU dots | convT1(pw) | convN1(v1,v2)  [2816 blocks]
__global__ __launch_bounds__(256, 4)
void k1_kernel(Args A)
{
    __shared__ alignas(16) char lds[16384];
    const int id = blockIdx.x, t = threadIdx.x;
    const size_t HO = (size_t)1024 * 512;
    if (id < 256) {
        gemm_G(A.k1w, A.k2w, A.q1w, A.q2w, A.GHi, lds, t, id, 256);
    } else if (id < 768) {                          // cls embed
        const int n = id - 256;
        const int tok = A.toks[n * Tn];
        float4 e = ((const float4*)(A.emb + (size_t)tok * Hd))[t];
        float4 p = ((const float4*)A.pos)[t];
        float f[4] = {e.x + p.x, e.y + p.y, e.z + p.z, e.w + p.w};
        ((float4*)(A.XclsF + (size_t)n * Hd))[t] = make_float4(f[0], f[1], f[2], f[3]);
        u16x4 hv, lv;
        #pragma unroll
        for (int j = 0; j < 4; ++j) {
            u16 h = f2bf(f[j]);
            hv[j] = h;
            lv[j] = f2bf(f[j] - bf2f(h));
        }
        *(u16x4*)(A.XclsHi + (size_t)n * Hd + t * 4) = hv;
        *(u16x4*)(A.XclsLo + (size_t)n * Hd + t * 4) = lv;
    } else if (id < 1280) {                         // bU = [Wk1@q1b | Wk2@q2b]
        const int b = id - 768;
        const int wave = t >> 6, lane = t & 63;
        const int jj = b * 4 + wave;
        const int head = jj >> 10, j = jj & 1023;
        const float* row = (head ? A.k2w : A.k1w) + (size_t)j * 512;
        const float* bqp = head ? A.q2b : A.q1b;
        float4 r0 = ((const float4*)row)[lane * 2];
        float4 r1 = ((const float4*)row)[lane * 2 + 1];
        float4 b0 = ((const float4*)bqp)[lane * 2];
        float4 b1 = ((const float4*)bqp)[lane * 2 + 1];
        float d = r0.x*b0.x + r0.y*b0.y + r0.z*b0.z + r0.w*b0.w
                + r1.x*b1.x + r1.y*b1.y + r1.z*b1.z + r1.w*b1.w;
        #pragma unroll
        for (int off = 32; off; off >>= 1) d += __shfl_xor(d, off);
        if (lane == 0) A.bU[jj] = d;
    } else if (id < 2304) {
        convT1_seg(A.pw, A.WpTHi, 1024, 1024, id - 1280, t, lds);
    } else if (id < 2560) {
        convN1_seg(A.v1w, A.WvNHi, id - 2304, t);
    } else {
        convN1_seg(A.v2w, A.WvNHi + HO, id - 2560, t);
    }
}

// K2: U GEMM | Wvp fold (1-term) | bvp | convT1(w1)              [4736 blocks]
__global__ __launch_bounds__(256, 4)
void k2_kernel(Args A)
{
    __shared__ alignas(16) char lds[32768];
    const int id = blockIdx.x, t = threadIdx.x;
    const size_t HO = (size_t)1024 * 512;
    if (id < 128)
        gemm_dev(A.XclsHi, A.XclsLo, 1024, 0, A.GHi, 1024, 0,
                 A.bU, A.U, nullptr, nullptr, 2048, 0, 0,
                 512, 2048, 1024, 1, 0, nullptr, 0, lds, t, id, 128);
    else if (id < 384)
        gemm_dev(A.WpTHi, nullptr, 1024, 512, A.WvNHi, 512, HO,
                 nullptr, nullptr, A.WvpHi, nullptr, 2048, 0, 1024,
                 1024, 1024, 512, 2, 8 | 16, nullptr, 0, lds, t, id - 128, 256);
    else if (id < 640) {
        const int wave = t >> 6, lane = t & 63;
        const int c = (id - 384) * 4 + wave;
        const int j0 = lane * 16;
        u16x8 h0 = *(const u16x8*)(A.WpTHi + (size_t)c * 1024 + j0);
        u16x8 h1 = *(const u16x8*)(A.WpTHi + (size_t)c * 1024 + j0 + 8);
        const float* bsrc = (j0 < 512) ? (A.v1b + j0) : (A.v2b + j0 - 512);
        float d = 0.f;
        #pragma unroll
        for (int j = 0; j < 8; ++j) d += bsrc[j] * bf2f(h0[j]);
        #pragma unroll
        for (int j = 0; j < 8; ++j) d += bsrc[8 + j] * bf2f(h1[j]);
        #pragma unroll
        for (int off = 32; off; off >>= 1) d += __shfl_xor(d, off);
        if (lane == 0) A.bvp[c] = d + A.pb[c];
    } else {
        convT1_seg(A.w1w, A.W1THi, 1024, 4096, id - 640, t, lds);
    }
}

// K3: single-pass attention, x cached in LDS as bf16             [512 blocks]
__global__ __launch_bounds__(512, 1)
void k3_kernel(Args A)
{
    __shared__ float us[2048];
    __shared__ float ps[128];
    __shared__ u16 xc[Tn * 1024];
    const int n = blockIdx.x, tid = threadIdx.x;
    ((float4*)us)[tid] = ((const float4*)(A.U + (size_t)n * 2048))[tid];
    __syncthreads();

    const int wave = tid >> 6, lane = tid & 63;
    const int* tk = A.toks + n * Tn;
    for (int s = wave; s < Tn; s += 8) {
        const int tok = tk[s];
        const float4* er = (const float4*)(A.emb + (size_t)tok * Hd);
        const float4* pr = (const float4*)(A.pos + (size_t)s * Hd);
        float d1 = 0.f, d2 = 0.f;
        #pragma unroll
        for (int i = 0; i < 4; ++i) {
            const int c = i * 64 + lane;
            float4 e = er[c], p = pr[c];
            float x0 = e.x + p.x, x1 = e.y + p.y, x2 = e.z + p.z, x3 = e.w + p.w;
            u16x4 xv;
            xv[0] = f2bf(x0); xv[1] = f2bf(x1); xv[2] = f2bf(x2); xv[3] = f2bf(x3);
            *(u16x4*)(xc + s * 1024 + c * 4) = xv;
            const float* u1 = us + c * 4;
            const float* u2 = us + 1024 + c * 4;
            d1 += x0 * u1[0] + x1 * u1[1] + x2 * u1[2] + x3 * u1[3];
            d2 += x0 * u2[0] + x1 * u2[1] + x2 * u2[2] + x3 * u2[3];
        }
        #pragma unroll
        for (int off = 32; off; off >>= 1) {
            d1 += __shfl_xor(d1, off);
            d2 += __shfl_xor(d2, off);
        }
        if (lane == 0) {
            ps[s]      = d1 * 0.044194173824159216f;   // 1/sqrt(512)
            ps[64 + s] = d2 * 0.044194173824159216f;
        }
    }
    __syncthreads();
    if (wave < 2) {
        float v = (lane < Tn) ? ps[wave * 64 + lane] : -INFINITY;
        float mx = v;
        #pragma unroll
        for (int off = 32; off; off >>= 1) mx = fmaxf(mx, __shfl_xor(mx, off));
        float e = (lane < Tn) ? __expf(v - mx) : 0.f;
        float sum = e;
        #pragma unroll
        for (int off = 32; off; off >>= 1) sum += __shfl_xor(sum, off);
        if (lane < Tn) ps[wave * 64 + lane] = e / sum;
    }
    __syncthreads();

    float a1x = 0.f, a1y = 0.f, a2x = 0.f, a2y = 0.f;
    for (int s = 0; s < Tn; ++s) {
        const float p1 = ps[s], p2 = ps[64 + s];
        u16x2 xv = *(const u16x2*)(xc + s * 1024 + tid * 2);
        const float x0 = bf2f(xv[0]), x1 = bf2f(xv[1]);
        a1x = fmaf(p1, x0, a1x); a1y = fmaf(p1, x1, a1y);
        a2x = fmaf(p2, x0, a2x); a2y = fmaf(p2, x1, a2y);
    }
    u16x2 h1, l1, h2, l2;
    u16 h;
    h = f2bf(a1x); h1[0] = h; l1[0] = f2bf(a1x - bf2f(h));
    h = f2bf(a1y); h1[1] = h; l1[1] = f2bf(a1y - bf2f(h));
    h = f2bf(a2x); h2[0] = h; l2[0] = f2bf(a2x - bf2f(h));
    h = f2bf(a2y); h2[1] = h; l2[1] = f2bf(a2y - bf2f(h));
    const size_t o = (size_t)n * 2048 + tid * 2;
    *(u16x2*)(A.YHi + o) = h1;          *(u16x2*)(A.YLo + o) = l1;
    *(u16x2*)(A.YHi + o + 1024) = h2;   *(u16x2*)(A.YLo + o + 1024) = l2;
}

// K4: Hb partials = Y @ Wvp^T (split-K=8) | convT1(w2)           [4608 blocks]
__global__ __launch_bounds__(256, 4)
void k4_kernel(Args A)
{
    __shared__ alignas(16) char lds[32768];
    const int id = blockIdx.x, t = threadIdx.x;
    if (id < 512)
        gemm_dev(A.YHi, A.YLo, 2048, 0, A.WvpHi, 2048, 0,
                 nullptr, nullptr, nullptr, nullptr, 0, 0, 0,
                 512, 1024, 2048, 8, 4, A.Cp, (size_t)Nb * Hd, lds, t, id, 512);
    else
        convT1_seg(A.w2w, A.W2THi, 4096, 1024, id - 512, t, lds);
}

// K5: Hb = sum Cp[0..7] + bvp + Xcls ; LN -> fp32 + planes       [512 blocks]
__global__ __launch_bounds__(256)
void k5_kernel(Args A)
{
    const int tid = threadIdx.x;
    const size_t base = (size_t)blockIdx.x * Hd;
    const size_t P = (size_t)Nb * Hd;
    float4 v = ((const float4*)A.bvp)[tid];
    {
        float4 xc = ((const float4*)(A.XclsF + base))[tid];
        v.x += xc.x; v.y += xc.y; v.z += xc.z; v.w += xc.w;
    }
    #pragma unroll
    for (int z = 0; z < 8; ++z) {
        float4 c = ((const float4*)(A.Cp + z * P + base))[tid];
        v.x += c.x; v.y += c.y; v.z += c.z; v.w += c.w;
    }
    float s = v.x + v.y + v.z + v.w;
    float q = v.x*v.x + v.y*v.y + v.z*v.z + v.w*v.w;
    #pragma unroll
    for (int off = 32; off; off >>= 1) {
        s += __shfl_xor(s, off);
        q += __shfl_xor(q, off);
    }
    __shared__ float ss[4], sq[4];
    const int lane = tid & 63, w = tid >> 6;
    if (lane == 0) { ss[w] = s; sq[w] = q; }
    __syncthreads();
    s = ss[0] + ss[1] + ss[2] + ss[3];
    q = sq[0] + sq[1] + sq[2] + sq[3];
    const float mean = s * (1.f / Hd);
    const float var = q * (1.f / Hd) - mean * mean;
    const float rstd = rsqrtf(var + 1e-5f);
    float4 gv = ((const float4*)A.lg)[tid];
    float4 bv = ((const float4*)A.lb)[tid];
    float f[4];
    f[0] = (v.x - mean) * rstd * gv.x + bv.x;
    f[1] = (v.y - mean) * rstd * gv.y + bv.y;
    f[2] = (v.z - mean) * rstd * gv.z + bv.z;
    f[3] = (v.w - mean) * rstd * gv.w + bv.w;
    ((float4*)(A.Hb + base))[tid] = make_float4(f[0], f[1], f[2], f[3]);
    u16x4 hv, lv;
    #pragma unroll
    for (int j = 0; j < 4; ++j) {
        u16 hh = f2bf(f[j]);
        hv[j] = hh;
        lv[j] = f2bf(f[j] - bf2f(hh));
    }
    *(u16x4*)(A.HbHi + base + tid * 4) = hv;
    *(u16x4*)(A.HbLo + base + tid * 4) = lv;
}

// K6: E = relu(Hb @ W1 + w1b) -> hi/lo planes                    [256 blocks]
__global__ __launch_bounds__(256, 4)
void k6_kernel(Args A)
{
    __shared__ alignas(16) char lds[32768];
    gemm_dev(A.HbHi, A.HbLo, 1024, 0, A.W1THi, 1024, 0,
             A.w1b, nullptr, A.EHi, A.ELo, 4096, 0, 0,
             512, 4096, 1024, 1, 3, nullptr, 0, lds, threadIdx.x, blockIdx.x, 256);
}

// K7: w2 partials = E @ W2^T (split-K=4)                         [256 blocks]
__global__ __launch_bounds__(256, 4)
void k7_kernel(Args A)
{
    __shared__ alignas(16) char lds[32768];
    gemm_dev(A.EHi, A.ELo, 4096, 0, A.W2THi, 4096, 0,
             nullptr, nullptr, nullptr, nullptr, 0, 0, 0,
             512, 1024, 4096, 4, 4, A.Cp, (size_t)Nb * Hd,
             lds, threadIdx.x, blockIdx.x, 256);
}

// K8: H2 = sum Cp[0..3] + w2b + Hb ; LN ; dot ; sigmoid           [512 blocks]
__global__ __launch_bounds__(256)
void k8_kernel(Args A)
{
    const int tid = threadIdx.x;
    const size_t base = (size_t)blockIdx.x * Hd;
    const size_t P = (size_t)Nb * Hd;
    float4 v = ((const float4*)A.w2b)[tid];
    {
        float4 hh = ((const float4*)(A.Hb + base))[tid];
        v.x += hh.x; v.y += hh.y; v.z += hh.z; v.w += hh.w;
    }
    #pragma unroll
    for (int z = 0; z < 4; ++z) {
        float4 c = ((const float4*)(A.Cp + z * P + base))[tid];
        v.x += c.x; v.y += c.y; v.z += c.z; v.w += c.w;
    }
    float s = v.x + v.y + v.z + v.w;
    float q = v.x*v.x + v.y*v.y + v.z*v.z + v.w*v.w;
    #pragma unroll
    for (int off = 32; off; off >>= 1) {
        s += __shfl_xor(s, off);
        q += __shfl_xor(q, off);
    }
    __shared__ float ss[4], sq[4], sd[4];
    const int lane = tid & 63, w = tid >> 6;
    if (lane == 0) { ss[w] = s; sq[w] = q; }
    __syncthreads();
    s = ss[0] + ss[1] + ss[2] + ss[3];
    q = sq[0] + sq[1] + sq[2] + sq[3];
    const float mean = s * (1.f / Hd);
    const float var = q * (1.f / Hd) - mean * mean;
    const float rstd = rsqrtf(var + 1e-5f);
    float4 gv = ((const float4*)A.lg)[tid];
    float4 bv = ((const float4*)A.lb)[tid];
    float4 wv = ((const float4*)A.flw)[tid];
    float d = ((v.x - mean) * rstd * gv.x + bv.x) * wv.x
            + ((v.y - mean) * rstd * gv.y + bv.y) * wv.y
            + ((v.z - mean) * rstd * gv.z + bv.z) * wv.z
            + ((v.w - mean) * rstd * gv.w + bv.w) * wv.w;
    #pragma unroll
    for (int off = 32; off; off >>= 1) d += __shfl_xor(d, off);
    if (lane == 0) sd[w] = d;
    __syncthreads();
    if (tid == 0) {
        float z = sd[0] + sd[1] + sd[2] + sd[3] + A.flb[0];
        A.out[blockIdx.x] = 1.f / (1.f + expf(-z));
    }
}

// ===========================================================================
// host
// ===========================================================================
extern "C" void kernel_launch(void* const* d_in, const int* in_sizes, int n_in,
                              void* d_out, int out_size, void* d_ws, size_t ws_size,
                              hipStream_t stream)
{
    Args A;
    A.toks = (const int*)d_in[0];
    A.emb  = (const float*)d_in[1];
    A.pos  = (const float*)d_in[2];
    A.q1w = (const float*)d_in[3];  A.q1b = (const float*)d_in[4];
    A.k1w = (const float*)d_in[5];
    A.v1w = (const float*)d_in[7];  A.v1b = (const float*)d_in[8];
    A.q2w = (const float*)d_in[9];  A.q2b = (const float*)d_in[10];
    A.k2w = (const float*)d_in[11];
    A.v2w = (const float*)d_in[13]; A.v2b = (const float*)d_in[14];
    A.pw  = (const float*)d_in[15]; A.pb  = (const float*)d_in[16];
    A.lg  = (const float*)d_in[17]; A.lb  = (const float*)d_in[18];
    A.w1w = (const float*)d_in[19]; A.w1b = (const float*)d_in[20];
    A.w2w = (const float*)d_in[21]; A.w2b = (const float*)d_in[22];
    A.flw = (const float*)d_in[23]; A.flb = (const float*)d_in[24];
    A.out = (float*)d_out;
    char* wsb = (char*)d_ws;

    size_t off = 0;
    auto alloc = [&](size_t bytes) { size_t o = off; off = (off + bytes + 255) & ~(size_t)255; return o; };

    A.GHi   = (u16*)(wsb + alloc(2048 * 1024 * 2));
    A.WpTHi = (u16*)(wsb + alloc(1024 * 1024 * 2));
    A.W1THi = (u16*)(wsb + alloc(4096 * 1024 * 2));
    A.W2THi = (u16*)(wsb + alloc(1024 * 4096 * 2));
    A.WvNHi = (u16*)(wsb + alloc(2 * 1024 * 512 * 2));
    A.WvpHi = (u16*)(wsb + alloc(1024 * 2048 * 2));
    A.bU    = (float*)(wsb + alloc(2048 * 4));
    A.bvp   = (float*)(wsb + alloc(1024 * 4));
    A.XclsF = (float*)(wsb + alloc((size_t)Nb * Hd * 4));
    A.XclsHi= (u16*)(wsb + alloc((size_t)Nb * Hd * 2));
    A.XclsLo= (u16*)(wsb + alloc((size_t)Nb * Hd * 2));
    A.U     = (float*)(wsb + alloc((size_t)Nb * 2048 * 4));
    A.YHi   = (u16*)(wsb + alloc((size_t)Nb * 2048 * 2));
    A.YLo   = (u16*)(wsb + alloc((size_t)Nb * 2048 * 2));
    A.Hb    = (float*)(wsb + alloc((size_t)Nb * Hd * 4));
    A.HbHi  = (u16*)(wsb + alloc((size_t)Nb * Hd * 2));
    A.HbLo  = (u16*)(wsb + alloc((size_t)Nb * Hd * 2));
    A.EHi   = (u16*)(wsb + alloc((size_t)Nb * 4096 * 2));
    A.ELo   = (u16*)(wsb + alloc((size_t)Nb * 4096 * 2));
    A.Cp    = (float*)(wsb + alloc((size_t)8 * Nb * Hd * 4));

    k1_kernel<<<2816, 256, 0, stream>>>(A);
    k2_kernel<<<4736, 256, 0, stream>>>(A);
    k3_kernel<<<512,  512, 0, stream>>>(A);
    k4_kernel<<<4608, 256, 0, stream>>>(A);
    k5_kernel<<<512,  256, 0, stream>>>(A);
    k6_kernel<<<256,  256, 0, stream>>>(A);
    k7_kernel<<<256,  256, 0, stream>>>(A);
    k8_kernel<<<512,  256, 0, stream>>>(A);
}

// Round 16
// 113.561 us; speedup vs baseline: 3.4416x; 1.0050x over previous
//
#include <hip/hip_runtime.h>
#include <math.h>

typedef float  f32x4  __attribute__((ext_vector_type(4)));
typedef short  bf16x8 __attribute__((ext_vector_type(8)));
typedef unsigned short u16;
typedef unsigned int   u32;
typedef unsigned short u16x2 __attribute__((ext_vector_type(2)));
typedef unsigned short u16x4 __attribute__((ext_vector_type(4)));
typedef unsigned short u16x8 __attribute__((ext_vector_type(8)));

constexpr int Tn = 43, Hd = 1024, Nb = 512;

__device__ __forceinline__ u16 f2bf(float f) {
    u32 u = __float_as_uint(f);
    u32 r = u + 0x7FFFu + ((u >> 16) & 1u);
    return (u16)(r >> 16);
}
__device__ __forceinline__ float bf2f(u16 h) {
    return __uint_as_float(((u32)h) << 16);
}
__device__ __forceinline__ void cvt8(const float* f, u16x8* hi, u16x8* lo) {
    #pragma unroll
    for (int j = 0; j < 8; ++j) {
        u16 h = f2bf(f[j]);
        (*hi)[j] = h;
        (*lo)[j] = f2bf(f[j] - bf2f(h));
    }
}
__device__ __forceinline__ void cvt8h(const float* f, u16x8* hi) {
    #pragma unroll
    for (int j = 0; j < 8; ++j) (*hi)[j] = f2bf(f[j]);
}

// ---------------------------------------------------------------------------
// convT1: fp32 [K][N] -> bf16 HI plane only, transposed [N][K]
// ---------------------------------------------------------------------------
__device__ __forceinline__ void convT1_seg(const float* __restrict__ W,
                                           u16* __restrict__ Hi,
                                           int K, int N, int local, int t, char* lds)
{
    float (*tile)[33] = (float(*)[33])lds;
    const int tn = N >> 5;
    const int k0 = (local / tn) << 5, n0 = (local % tn) << 5;
    {
        int kk = t >> 3, nn = (t & 7) * 4;
        float4 v = *(const float4*)(W + (size_t)(k0 + kk) * N + n0 + nn);
        tile[kk][nn] = v.x; tile[kk][nn + 1] = v.y;
        tile[kk][nn + 2] = v.z; tile[kk][nn + 3] = v.w;
    }
    __syncthreads();
    {
        int nn = t >> 3, kk = (t & 7) * 4;
        u16x4 h;
        #pragma unroll
        for (int j = 0; j < 4; ++j) h[j] = f2bf(tile[kk + j][nn]);
        *(u16x4*)(Hi + (size_t)(n0 + nn) * K + k0 + kk) = h;
    }
}

// ---------------------------------------------------------------------------
// convN1: natural layout fp32 flat -> HI plane only (1024x512 per matrix)
// ---------------------------------------------------------------------------
__device__ __forceinline__ void convN1_seg(const float* __restrict__ src,
                                           u16* __restrict__ Hi, int local, int t)
{
    const size_t e = ((size_t)local * 256 + t) * 8;
    const float4* p = (const float4*)(src + e);
    float4 v0 = p[0], v1 = p[1];
    float f[8] = {v0.x, v0.y, v0.z, v0.w, v1.x, v1.y, v1.z, v1.w};
    u16x8 hv;
    cvt8h(f, &hv);
    *(u16x8*)(Hi + e) = hv;
}

// ---------------------------------------------------------------------------
// device GEMM: C = A@B^T.  A = hi(+lo) activation planes, B = HI weight plane.
// 2-term (1-term if A hi-only). 64x128 tile, BK=64, 4 waves, reg-staged.
// flags: 1=RELU 2=PLANES(hi+lo out) 4=SPLIT-K 8=A-hi-only 16=PLANES hi-only
// ---------------------------------------------------------------------------
__device__ __forceinline__ void gemm_dev(
    const u16* Ahi, const u16* Alo, int lda, size_t az,
    const u16* Bhi, int ldb, size_t bz,
    const float* bias, float* C, u16* CHi, u16* CLo, int ldc, int crz, int ccz,
    int M, int N, int K, int nz, int flags,
    float* Cp, size_t pstride, char* lds, int tid, int t0, int tstride)
{
    const bool RELU = flags & 1, PLANES = flags & 2, SPLIT = flags & 4;
    const bool A1 = flags & 8, PL1 = flags & 16;
    const int ncol = N >> 7;
    const int tpz = (M >> 6) * ncol;
    const int ntiles = nz * tpz;
    const int BOFF = A1 ? 8192 : 16384;      // B-plane base in LDS

    const int ra = tid >> 2, ga = tid & 3;
    const int rb = tid >> 1, gb = (tid & 1) << 1;
    const int wA  = ((ra >> 4) << 10) | (ga << 8) | ((((ra & 15) ^ (ga << 1)) & 15) << 4);
    const int wB0 = ((rb >> 4) << 10) | (gb << 8) | ((((rb & 15) ^ (gb << 1)) & 15) << 4);
    const int wB1 = ((rb >> 4) << 10) | ((gb + 1) << 8) | ((((rb & 15) ^ ((gb + 1) << 1)) & 15) << 4);
    const int wv = tid >> 6, lane = tid & 63;
    const int wr = wv >> 1, wc = wv & 1;
    const int l15 = lane & 15, l4 = lane >> 4;
    const int rsw = (l15 ^ (l4 << 1)) << 4;
    int fA[2], fB[4];
    #pragma unroll
    for (int m = 0; m < 2; ++m) fA[m] = (((wr << 1) + m) << 10) | (l4 << 8) | rsw;
    #pragma unroll
    for (int n = 0; n < 4; ++n) fB[n] = (((wc << 2) + n) << 10) | (l4 << 8) | rsw;

    for (int t = t0; t < ntiles; t += tstride) {
        const int z = t / tpz, r = t - z * tpz;
        const int tm = r / ncol;
        const int bm = tm << 6, bn = (r - tm * ncol) << 7;
        int kc = K, kb = 0;
        const u16 *ah = Ahi, *al = Alo, *bh = Bhi;
        if (SPLIT) { kc = K / nz; kb = z * kc; }
        else { ah += z * az; if (!A1) al += z * az; bh += z * bz; }

        const u16* pAh = ah + (size_t)(bm + ra) * lda + kb + ga * 8;
        const u16* pAl = A1 ? pAh : al + (size_t)(bm + ra) * lda + kb + ga * 8;
        const u16* pBh = bh + (size_t)(bn + rb) * ldb + kb + gb * 8;

        f32x4 acc[2][4] = {};

        // prologue: load k-step 0 (two 32-k halves) into registers
        uint4 sAh0 = *(const uint4*)pAh,        sAh1 = *(const uint4*)(pAh + 32);
        uint4 sAl0, sAl1;
        if (!A1) { sAl0 = *(const uint4*)pAl;   sAl1 = *(const uint4*)(pAl + 32); }
        uint4 sB00 = *(const uint4*)pBh,        sB01 = *(const uint4*)(pBh + 8);
        uint4 sB10 = *(const uint4*)(pBh + 32), sB11 = *(const uint4*)(pBh + 40);

        for (int k0 = 0; k0 < kc; k0 += 64) {
            __syncthreads();
            *(uint4*)(lds + wA)        = sAh0;
            *(uint4*)(lds + 4096 + wA) = sAh1;
            if (!A1) {
                *(uint4*)(lds + 8192 + wA)  = sAl0;
                *(uint4*)(lds + 12288 + wA) = sAl1;
            }
            *(uint4*)(lds + BOFF + wB0)        = sB00;
            *(uint4*)(lds + BOFF + wB1)        = sB01;
            *(uint4*)(lds + BOFF + 8192 + wB0) = sB10;
            *(uint4*)(lds + BOFF + 8192 + wB1) = sB11;
            __syncthreads();
            if (k0 + 64 < kc) {
                pAh += 64; pBh += 64;
                sAh0 = *(const uint4*)pAh;        sAh1 = *(const uint4*)(pAh + 32);
                if (!A1) {
                    pAl += 64;
                    sAl0 = *(const uint4*)pAl;    sAl1 = *(const uint4*)(pAl + 32);
                }
                sB00 = *(const uint4*)pBh;        sB01 = *(const uint4*)(pBh + 8);
                sB10 = *(const uint4*)(pBh + 32); sB11 = *(const uint4*)(pBh + 40);
            }
            #pragma unroll
            for (int h = 0; h < 2; ++h) {
                bf16x8 a8[2], c8[2], b8[4];
                #pragma unroll
                for (int m = 0; m < 2; ++m) {
                    a8[m] = *(const bf16x8*)(lds + (h << 12) + fA[m]);
                    if (!A1) c8[m] = *(const bf16x8*)(lds + 8192 + (h << 12) + fA[m]);
                }
                #pragma unroll
                for (int n = 0; n < 4; ++n)
                    b8[n] = *(const bf16x8*)(lds + BOFF + (h << 13) + fB[n]);
                #pragma unroll
                for (int m = 0; m < 2; ++m)
                    #pragma unroll
                    for (int n = 0; n < 4; ++n) {
                        acc[m][n] = __builtin_amdgcn_mfma_f32_16x16x32_bf16(a8[m], b8[n], acc[m][n], 0, 0, 0);
                        if (!A1)
                            acc[m][n] = __builtin_amdgcn_mfma_f32_16x16x32_bf16(c8[m], b8[n], acc[m][n], 0, 0, 0);
                    }
            }
        }

        #pragma unroll
        for (int n = 0; n < 4; ++n) {
            const int col = bn + (wc << 6) + n * 16 + l15;
            const float bv = (!SPLIT && bias) ? bias[col] : 0.f;
            const int colz = SPLIT ? col : col + z * ccz;
            #pragma unroll
            for (int m = 0; m < 2; ++m) {
                const int row0 = bm + (wr << 5) + m * 16 + l4 * 4;
                #pragma unroll
                for (int rg = 0; rg < 4; ++rg) {
                    const int row = row0 + rg;
                    float v = acc[m][n][rg];
                    if (SPLIT) {
                        Cp[z * pstride + (size_t)row * N + col] = v;
                    } else {
                        const int rowz = row + z * crz;
                        v += bv;
                        if (RELU) v = fmaxf(v, 0.f);
                        if (PL1) {
                            CHi[(size_t)rowz * ldc + colz] = f2bf(v);
                        } else if (PLANES) {
                            u16 hh = f2bf(v);
                            CHi[(size_t)rowz * ldc + colz] = hh;
                            CLo[(size_t)rowz * ldc + colz] = f2bf(v - bf2f(hh));
                        } else {
                            C[(size_t)rowz * ldc + colz] = v;
                        }
                    }
                }
            }
        }
    }
}

// ---------------------------------------------------------------------------
// gemm_G: G_h = Wk_h @ Wq_h^T from fp32 sources, convert-on-stage (reg path).
// A = Wk hi+lo, B = Wq hi only -> 2-term. Output G HI plane only. (BK=32)
// ---------------------------------------------------------------------------
__device__ __forceinline__ void gemm_G(
    const float* k1w, const float* k2w, const float* q1w, const float* q2w,
    u16* GHi, char* lds, int tid, int t0, int tstride)
{
    const int ra = tid >> 2, ga = tid & 3;
    const int rb = tid >> 1, gb = (tid & 1) << 1;
    const int wA  = ((ra >> 4) << 10) | (ga << 8) | ((((ra & 15) ^ (ga << 1)) & 15) << 4);
    const int wB0 = ((rb >> 4) << 10) | (gb << 8) | ((((rb & 15) ^ (gb << 1)) & 15) << 4);
    const int wB1 = ((rb >> 4) << 10) | ((gb + 1) << 8) | ((((rb & 15) ^ ((gb + 1) << 1)) & 15) << 4);
    const int wv = tid >> 6, lane = tid & 63;
    const int wr = wv >> 1, wc = wv & 1;
    const int l15 = lane & 15, l4 = lane >> 4;
    const int rsw = (l15 ^ (l4 << 1)) << 4;
    int fA[2], fB[4];
    #pragma unroll
    for (int m = 0; m < 2; ++m) fA[m] = (((wr << 1) + m) << 10) | (l4 << 8) | rsw;
    #pragma unroll
    for (int n = 0; n < 4; ++n) fB[n] = (((wc << 2) + n) << 10) | (l4 << 8) | rsw;

    for (int t = t0; t < 256; t += tstride) {
        const int z = t >> 7, r = t & 127;
        const int bm = (r >> 3) << 6, bn = (r & 7) << 7;
        const float* pA = (z ? k2w : k1w) + (size_t)(bm + ra) * 512 + ga * 8;
        const float* pB = (z ? q2w : q1w) + (size_t)(bn + rb) * 512 + gb * 8;

        f32x4 acc[2][4] = {};
        float4 a0 = ((const float4*)pA)[0], a1 = ((const float4*)pA)[1];
        float4 b0 = ((const float4*)pB)[0], b1 = ((const float4*)pB)[1];
        float4 b2 = ((const float4*)pB)[2], b3 = ((const float4*)pB)[3];

        for (int k0 = 0; k0 < 512; k0 += 32) {
            u16x8 hi, lo;
            float fa[8] = {a0.x, a0.y, a0.z, a0.w, a1.x, a1.y, a1.z, a1.w};
            float fb[8] = {b0.x, b0.y, b0.z, b0.w, b1.x, b1.y, b1.z, b1.w};
            float fc[8] = {b2.x, b2.y, b2.z, b2.w, b3.x, b3.y, b3.z, b3.w};
            __syncthreads();
            cvt8(fa, &hi, &lo);
            *(u16x8*)(lds + wA) = hi;
            *(u16x8*)(lds + 4096 + wA) = lo;
            cvt8h(fb, &hi);
            *(u16x8*)(lds + 8192 + wB0) = hi;
            cvt8h(fc, &hi);
            *(u16x8*)(lds + 8192 + wB1) = hi;
            __syncthreads();
            if (k0 + 32 < 512) {
                pA += 32; pB += 32;
                a0 = ((const float4*)pA)[0]; a1 = ((const float4*)pA)[1];
                b0 = ((const float4*)pB)[0]; b1 = ((const float4*)pB)[1];
                b2 = ((const float4*)pB)[2]; b3 = ((const float4*)pB)[3];
            }
            bf16x8 a8[2], c8[2], b8[4];
            #pragma unroll
            for (int m = 0; m < 2; ++m) {
                a8[m] = *(const bf16x8*)(lds + fA[m]);
                c8[m] = *(const bf16x8*)(lds + 4096 + fA[m]);
            }
            #pragma unroll
            for (int n = 0; n < 4; ++n)
                b8[n] = *(const bf16x8*)(lds + 8192 + fB[n]);
            #pragma unroll
            for (int m = 0; m < 2; ++m)
                #pragma unroll
                for (int n = 0; n < 4; ++n) {
                    acc[m][n] = __builtin_amdgcn_mfma_f32_16x16x32_bf16(a8[m], b8[n], acc[m][n], 0, 0, 0);
                    acc[m][n] = __builtin_amdgcn_mfma_f32_16x16x32_bf16(c8[m], b8[n], acc[m][n], 0, 0, 0);
                }
        }

        #pragma unroll
        for (int n = 0; n < 4; ++n) {
            const int col = bn + (wc << 6) + n * 16 + l15;
            #pragma unroll
            for (int m = 0; m < 2; ++m) {
                const int row0 = bm + (wr << 5) + m * 16 + l4 * 4;
                #pragma unroll
                for (int rg = 0; rg < 4; ++rg) {
                    const int row = z * 1024 + row0 + rg;
                    GHi[(size_t)row * 1024 + col] = f2bf(acc[m][n][rg]);
                }
            }
        }
    }
}

// ===========================================================================
// shared arg block
// ===========================================================================
struct Args {
    const int* toks; const float* emb; const float* pos;
    const float *q1w, *q2w, *k1w, *k2w, *v1w, *v2w, *pw, *w1w, *w2w;
    const float *q1b, *q2b, *v1b, *v2b, *pb, *lg, *lb, *w1b, *w2b, *flw, *flb;
    u16 *GHi, *WpTHi, *W1THi, *W2THi, *WvNHi, *WvpHi;
    float *bU, *bvp;
    float* XclsF; u16 *XclsHi, *XclsLo;
    float* U; u16 *YHi, *YLo;
    float* Hb; u16 *HbHi, *HbLo;
    u16 *EHi, *ELo;
    float* Cp;
    float* out;
};

// K1: G GEMM | cls embed | bU dots | convT1(pw) | convN1(v1,v2)  [2816 blocks]
__global__ __launch_bounds__(256, 4)
void k1_kernel(Args A)
{
    __shared__ alignas(16) char lds[16384];
    const int id = blockIdx.x, t = threadIdx.x;
    const size_t HO = (size_t)1024 * 512;
    if (id < 256) {
        gemm_G(A.k1w, A.k2w, A.q1w, A.q2w, A.GHi, lds, t, id, 256);
    } else if (id < 768) {                          // cls embed
        const int n = id - 256;
        const int tok = A.toks[n * Tn];
        float4 e = ((const float4*)(A.emb + (size_t)tok * Hd))[t];
        float4 p = ((const float4*)A.pos)[t];
        float f[4] = {e.x + p.x, e.y + p.y, e.z + p.z, e.w + p.w};
        ((float4*)(A.XclsF + (size_t)n * Hd))[t] = make_float4(f[0], f[1], f[2], f[3]);
        u16x4 hv, lv;
        #pragma unroll
        for (int j = 0; j < 4; ++j) {
            u16 h = f2bf(f[j]);
            hv[j] = h;
            lv[j] = f2bf(f[j] - bf2f(h));
        }
        *(u16x4*)(A.XclsHi + (size_t)n * Hd + t * 4) = hv;
        *(u16x4*)(A.XclsLo + (size_t)n * Hd + t * 4) = lv;
    } else if (id < 1280) {                         // bU = [Wk1@q1b | Wk2@q2b]
        const int b = id - 768;
        const int wave = t >> 6, lane = t & 63;
        const int jj = b * 4 + wave;
        const int head = jj >> 10, j = jj & 1023;
        const float* row = (head ? A.k2w : A.k1w) + (size_t)j * 512;
        const float* bqp = head ? A.q2b : A.q1b;
        float4 r0 = ((const float4*)row)[lane * 2];
        float4 r1 = ((const float4*)row)[lane * 2 + 1];
        float4 b0 = ((const float4*)bqp)[lane * 2];
        float4 b1 = ((const float4*)bqp)[lane * 2 + 1];
        float d = r0.x*b0.x + r0.y*b0.y + r0.z*b0.z + r0.w*b0.w
                + r1.x*b1.x + r1.y*b1.y + r1.z*b1.z + r1.w*b1.w;
        #pragma unroll
        for (int off = 32; off; off >>= 1) d += __shfl_xor(d, off);
        if (lane == 0) A.bU[jj] = d;
    } else if (id < 2304) {
        convT1_seg(A.pw, A.WpTHi, 1024, 1024, id - 1280, t, lds);
    } else if (id < 2560) {
        convN1_seg(A.v1w, A.WvNHi, id - 2304, t);
    } else {
        convN1_seg(A.v2w, A.WvNHi + HO, id - 2560, t);
    }
}

// K2: U GEMM | Wvp fold (1-term) | bvp | convT1(w1)              [4736 blocks]
__global__ __launch_bounds__(256, 4)
void k2_kernel(Args A)
{
    __shared__ alignas(16) char lds[32768];
    const int id = blockIdx.x, t = threadIdx.x;
    const size_t HO = (size_t)1024 * 512;
    if (id < 128)
        gemm_dev(A.XclsHi, A.XclsLo, 1024, 0, A.GHi, 1024, 0,
                 A.bU, A.U, nullptr, nullptr, 2048, 0, 0,
                 512, 2048, 1024, 1, 0, nullptr, 0, lds, t, id, 128);
    else if (id < 384)
        gemm_dev(A.WpTHi, nullptr, 1024, 512, A.WvNHi, 512, HO,
                 nullptr, nullptr, A.WvpHi, nullptr, 2048, 0, 1024,
                 1024, 1024, 512, 2, 8 | 16, nullptr, 0, lds, t, id - 128, 256);
    else if (id < 640) {
        const int wave = t >> 6, lane = t & 63;
        const int c = (id - 384) * 4 + wave;
        const int j0 = lane * 16;
        u16x8 h0 = *(const u16x8*)(A.WpTHi + (size_t)c * 1024 + j0);
        u16x8 h1 = *(const u16x8*)(A.WpTHi + (size_t)c * 1024 + j0 + 8);
        const float* bsrc = (j0 < 512) ? (A.v1b + j0) : (A.v2b + j0 - 512);
        float d = 0.f;
        #pragma unroll
        for (int j = 0; j < 8; ++j) d += bsrc[j] * bf2f(h0[j]);
        #pragma unroll
        for (int j = 0; j < 8; ++j) d += bsrc[8 + j] * bf2f(h1[j]);
        #pragma unroll
        for (int off = 32; off; off >>= 1) d += __shfl_xor(d, off);
        if (lane == 0) A.bvp[c] = d + A.pb[c];
    } else {
        convT1_seg(A.w1w, A.W1THi, 1024, 4096, id - 640, t, lds);
    }
}

// K3: single-pass attention, x cached in LDS as bf16             [512 blocks]
__global__ __launch_bounds__(512, 1)
void k3_kernel(Args A)
{
    __shared__ float us[2048];
    __shared__ float ps[128];
    __shared__ u16 xc[Tn * 1024];
    const int n = blockIdx.x, tid = threadIdx.x;
    ((float4*)us)[tid] = ((const float4*)(A.U + (size_t)n * 2048))[tid];
    __syncthreads();

    const int wave = tid >> 6, lane = tid & 63;
    const int* tk = A.toks + n * Tn;
    for (int s = wave; s < Tn; s += 8) {
        const int tok = tk[s];
        const float4* er = (const float4*)(A.emb + (size_t)tok * Hd);
        const float4* pr = (const float4*)(A.pos + (size_t)s * Hd);
        float d1 = 0.f, d2 = 0.f;
        #pragma unroll
        for (int i = 0; i < 4; ++i) {
            const int c = i * 64 + lane;
            float4 e = er[c], p = pr[c];
            float x0 = e.x + p.x, x1 = e.y + p.y, x2 = e.z + p.z, x3 = e.w + p.w;
            u16x4 xv;
            xv[0] = f2bf(x0); xv[1] = f2bf(x1); xv[2] = f2bf(x2); xv[3] = f2bf(x3);
            *(u16x4*)(xc + s * 1024 + c * 4) = xv;
            const float* u1 = us + c * 4;
            const float* u2 = us + 1024 + c * 4;
            d1 += x0 * u1[0] + x1 * u1[1] + x2 * u1[2] + x3 * u1[3];
            d2 += x0 * u2[0] + x1 * u2[1] + x2 * u2[2] + x3 * u2[3];
        }
        #pragma unroll
        for (int off = 32; off; off >>= 1) {
            d1 += __shfl_xor(d1, off);
            d2 += __shfl_xor(d2, off);
        }
        if (lane == 0) {
            ps[s]      = d1 * 0.044194173824159216f;   // 1/sqrt(512)
            ps[64 + s] = d2 * 0.044194173824159216f;
        }
    }
    __syncthreads();
    if (wave < 2) {
        float v = (lane < Tn) ? ps[wave * 64 + lane] : -INFINITY;
        float mx = v;
        #pragma unroll
        for (int off = 32; off; off >>= 1) mx = fmaxf(mx, __shfl_xor(mx, off));
        float e = (lane < Tn) ? __expf(v - mx) : 0.f;
        float sum = e;
        #pragma unroll
        for (int off = 32; off; off >>= 1) sum += __shfl_xor(sum, off);
        if (lane < Tn) ps[wave * 64 + lane] = e / sum;
    }
    __syncthreads();

    float a1x = 0.f, a1y = 0.f, a2x = 0.f, a2y = 0.f;
    for (int s = 0; s < Tn; ++s) {
        const float p1 = ps[s], p2 = ps[64 + s];
        u16x2 xv = *(const u16x2*)(xc + s * 1024 + tid * 2);
        const float x0 = bf2f(xv[0]), x1 = bf2f(xv[1]);
        a1x = fmaf(p1, x0, a1x); a1y = fmaf(p1, x1, a1y);
        a2x = fmaf(p2, x0, a2x); a2y = fmaf(p2, x1, a2y);
    }
    u16x2 h1, l1, h2, l2;
    u16 h;
    h = f2bf(a1x); h1[0] = h; l1[0] = f2bf(a1x - bf2f(h));
    h = f2bf(a1y); h1[1] = h; l1[1] = f2bf(a1y - bf2f(h));
    h = f2bf(a2x); h2[0] = h; l2[0] = f2bf(a2x - bf2f(h));
    h = f2bf(a2y); h2[1] = h; l2[1] = f2bf(a2y - bf2f(h));
    const size_t o = (size_t)n * 2048 + tid * 2;
    *(u16x2*)(A.YHi + o) = h1;          *(u16x2*)(A.YLo + o) = l1;
    *(u16x2*)(A.YHi + o + 1024) = h2;   *(u16x2*)(A.YLo + o + 1024) = l2;
}

// K4: Hb partials = Y @ Wvp^T (split-K=8)                        [512 blocks]
__global__ __launch_bounds__(256, 4)
void k4_kernel(Args A)
{
    __shared__ alignas(16) char lds[32768];
    gemm_dev(A.YHi, A.YLo, 2048, 0, A.WvpHi, 2048, 0,
             nullptr, nullptr, nullptr, nullptr, 0, 0, 0,
             512, 1024, 2048, 8, 4, A.Cp, (size_t)Nb * Hd,
             lds, threadIdx.x, blockIdx.x, 512);
}

// K5: Hb = sum Cp[0..7] + bvp + Xcls ; LN -> fp32 + planes       [512 blocks]
__global__ __launch_bounds__(256)
void k5_kernel(Args A)
{
    const int tid = threadIdx.x;
    const size_t base = (size_t)blockIdx.x * Hd;
    const size_t P = (size_t)Nb * Hd;
    float4 v = ((const float4*)A.bvp)[tid];
    {
        float4 xc = ((const float4*)(A.XclsF + base))[tid];
        v.x += xc.x; v.y += xc.y; v.z += xc.z; v.w += xc.w;
    }
    #pragma unroll
    for (int z = 0; z < 8; ++z) {
        float4 c = ((const float4*)(A.Cp + z * P + base))[tid];
        v.x += c.x; v.y += c.y; v.z += c.z; v.w += c.w;
    }
    float s = v.x + v.y + v.z + v.w;
    float q = v.x*v.x + v.y*v.y + v.z*v.z + v.w*v.w;
    #pragma unroll
    for (int off = 32; off; off >>= 1) {
        s += __shfl_xor(s, off);
        q += __shfl_xor(q, off);
    }
    __shared__ float ss[4], sq[4];
    const int lane = tid & 63, w = tid >> 6;
    if (lane == 0) { ss[w] = s; sq[w] = q; }
    __syncthreads();
    s = ss[0] + ss[1] + ss[2] + ss[3];
    q = sq[0] + sq[1] + sq[2] + sq[3];
    const float mean = s * (1.f / Hd);
    const float var = q * (1.f / Hd) - mean * mean;
    const float rstd = rsqrtf(var + 1e-5f);
    float4 gv = ((const float4*)A.lg)[tid];
    float4 bv = ((const float4*)A.lb)[tid];
    float f[4];
    f[0] = (v.x - mean) * rstd * gv.x + bv.x;
    f[1] = (v.y - mean) * rstd * gv.y + bv.y;
    f[2] = (v.z - mean) * rstd * gv.z + bv.z;
    f[3] = (v.w - mean) * rstd * gv.w + bv.w;
    ((float4*)(A.Hb + base))[tid] = make_float4(f[0], f[1], f[2], f[3]);
    u16x4 hv, lv;
    #pragma unroll
    for (int j = 0; j < 4; ++j) {
        u16 hh = f2bf(f[j]);
        hv[j] = hh;
        lv[j] = f2bf(f[j] - bf2f(hh));
    }
    *(u16x4*)(A.HbHi + base + tid * 4) = hv;
    *(u16x4*)(A.HbLo + base + tid * 4) = lv;
}

// K6: E = relu(Hb @ W1 + w1b) -> hi/lo planes | convT1(w2)       [4352 blocks]
// w2 conv rides here: W2THi is only read by K7, and K6's 256 GEMM blocks
// leave ~3/4 of the CUs idle — free overlap, off K4's critical path.
__global__ __launch_bounds__(256, 4)
void k6_kernel(Args A)
{
    __shared__ alignas(16) char lds[32768];
    const int id = blockIdx.x, t = threadIdx.x;
    if (id < 256)
        gemm_dev(A.HbHi, A.HbLo, 1024, 0, A.W1THi, 1024, 0,
                 A.w1b, nullptr, A.EHi, A.ELo, 4096, 0, 0,
                 512, 4096, 1024, 1, 3, nullptr, 0, lds, t, id, 256);
    else
        convT1_seg(A.w2w, A.W2THi, 4096, 1024, id - 256, t, lds);
}

// K7: w2 partials = E @ W2^T (split-K=4)                         [256 blocks]
__global__ __launch_bounds__(256, 4)
void k7_kernel(Args A)
{
    __shared__ alignas(16) char lds[32768];
    gemm_dev(A.EHi, A.ELo, 4096, 0, A.W2THi, 4096, 0,
             nullptr, nullptr, nullptr, nullptr, 0, 0, 0,
             512, 1024, 4096, 4, 4, A.Cp, (size_t)Nb * Hd,
             lds, threadIdx.x, blockIdx.x, 256);
}

// K8: H2 = sum Cp[0..3] + w2b + Hb ; LN ; dot ; sigmoid           [512 blocks]
__global__ __launch_bounds__(256)
void k8_kernel(Args A)
{
    const int tid = threadIdx.x;
    const size_t base = (size_t)blockIdx.x * Hd;
    const size_t P = (size_t)Nb * Hd;
    float4 v = ((const float4*)A.w2b)[tid];
    {
        float4 hh = ((const float4*)(A.Hb + base))[tid];
        v.x += hh.x; v.y += hh.y; v.z += hh.z; v.w += hh.w;
    }
    #pragma unroll
    for (int z = 0; z < 4; ++z) {
        float4 c = ((const float4*)(A.Cp + z * P + base))[tid];
        v.x += c.x; v.y += c.y; v.z += c.z; v.w += c.w;
    }
    float s = v.x + v.y + v.z + v.w;
    float q = v.x*v.x + v.y*v.y + v.z*v.z + v.w*v.w;
    #pragma unroll
    for (int off = 32; off; off >>= 1) {
        s += __shfl_xor(s, off);
        q += __shfl_xor(q, off);
    }
    __shared__ float ss[4], sq[4], sd[4];
    const int lane = tid & 63, w = tid >> 6;
    if (lane == 0) { ss[w] = s; sq[w] = q; }
    __syncthreads();
    s = ss[0] + ss[1] + ss[2] + ss[3];
    q = sq[0] + sq[1] + sq[2] + sq[3];
    const float mean = s * (1.f / Hd);
    const float var = q * (1.f / Hd) - mean * mean;
    const float rstd = rsqrtf(var + 1e-5f);
    float4 gv = ((const float4*)A.lg)[tid];
    float4 bv = ((const float4*)A.lb)[tid];
    float4 wv = ((const float4*)A.flw)[tid];
    float d = ((v.x - mean) * rstd * gv.x + bv.x) * wv.x
            + ((v.y - mean) * rstd * gv.y + bv.y) * wv.y
            + ((v.z - mean) * rstd * gv.z + bv.z) * wv.z
            + ((v.w - mean) * rstd * gv.w + bv.w) * wv.w;
    #pragma unroll
    for (int off = 32; off; off >>= 1) d += __shfl_xor(d, off);
    if (lane == 0) sd[w] = d;
    __syncthreads();
    if (tid == 0) {
        float z = sd[0] + sd[1] + sd[2] + sd[3] + A.flb[0];
        A.out[blockIdx.x] = 1.f / (1.f + expf(-z));
    }
}

// ===========================================================================
// host
// ===========================================================================
extern "C" void kernel_launch(void* const* d_in, const int* in_sizes, int n_in,
                              void* d_out, int out_size, void* d_ws, size_t ws_size,
                              hipStream_t stream)
{
    Args A;
    A.toks = (const int*)d_in[0];
    A.emb  = (const float*)d_in[1];
    A.pos  = (const float*)d_in[2];
    A.q1w = (const float*)d_in[3];  A.q1b = (const float*)d_in[4];
    A.k1w = (const float*)d_in[5];
    A.v1w = (const float*)d_in[7];  A.v1b = (const float*)d_in[8];
    A.q2w = (const float*)d_in[9];  A.q2b = (const float*)d_in[10];
    A.k2w = (const float*)d_in[11];
    A.v2w = (const float*)d_in[13]; A.v2b = (const float*)d_in[14];
    A.pw  = (const float*)d_in[15]; A.pb  = (const float*)d_in[16];
    A.lg  = (const float*)d_in[17]; A.lb  = (const float*)d_in[18];
    A.w1w = (const float*)d_in[19]; A.w1b = (const float*)d_in[20];
    A.w2w = (const float*)d_in[21]; A.w2b = (const float*)d_in[22];
    A.flw = (const float*)d_in[23]; A.flb = (const float*)d_in[24];
    A.out = (float*)d_out;
    char* wsb = (char*)d_ws;

    size_t off = 0;
    auto alloc = [&](size_t bytes) { size_t o = off; off = (off + bytes + 255) & ~(size_t)255; return o; };

    A.GHi   = (u16*)(wsb + alloc(2048 * 1024 * 2));
    A.WpTHi = (u16*)(wsb + alloc(1024 * 1024 * 2));
    A.W1THi = (u16*)(wsb + alloc(4096 * 1024 * 2));
    A.W2THi = (u16*)(wsb + alloc(1024 * 4096 * 2));
    A.WvNHi = (u16*)(wsb + alloc(2 * 1024 * 512 * 2));
    A.WvpHi = (u16*)(wsb + alloc(1024 * 2048 * 2));
    A.bU    = (float*)(wsb + alloc(2048 * 4));
    A.bvp   = (float*)(wsb + alloc(1024 * 4));
    A.XclsF = (float*)(wsb + alloc((size_t)Nb * Hd * 4));
    A.XclsHi= (u16*)(wsb + alloc((size_t)Nb * Hd * 2));
    A.XclsLo= (u16*)(wsb + alloc((size_t)Nb * Hd * 2));
    A.U     = (float*)(wsb + alloc((size_t)Nb * 2048 * 4));
    A.YHi   = (u16*)(wsb + alloc((size_t)Nb * 2048 * 2));
    A.YLo   = (u16*)(wsb + alloc((size_t)Nb * 2048 * 2));
    A.Hb    = (float*)(wsb + alloc((size_t)Nb * Hd * 4));
    A.HbHi  = (u16*)(wsb + alloc((size_t)Nb * Hd * 2));
    A.HbLo  = (u16*)(wsb + alloc((size_t)Nb * Hd * 2));
    A.EHi   = (u16*)(wsb + alloc((size_t)Nb * 4096 * 2));
    A.ELo   = (u16*)(wsb + alloc((size_t)Nb * 4096 * 2));
    A.Cp    = (float*)(wsb + alloc((size_t)8 * Nb * Hd * 4));

    k1_kernel<<<2816, 256, 0, stream>>>(A);
    k2_kernel<<<4736, 256, 0, stream>>>(A);
    k3_kernel<<<512,  512, 0, stream>>>(A);
    k4_kernel<<<512,  256, 0, stream>>>(A);
    k5_kernel<<<512,  256, 0, stream>>>(A);
    k6_kernel<<<4352, 256, 0, stream>>>(A);
    k7_kernel<<<256,  256, 0, stream>>>(A);
    k8_kernel<<<512,  256, 0, stream>>>(A);
}